// Round 5
// baseline (8147.285 us; speedup 1.0000x reference)
//
#include <hip/hip_runtime.h>
#include <math.h>

// SpatialGRU persistent-wavefront kernel. B=64, C=16, L=64, R=64, U=64, D=208.
// 64 persistent blocks, block = grid row l; cells (l, r=0..63) sequential.
// Cross-block dep (top row): payload via sc0sc1 write-through stores (explicit
// vmcnt drain) read by fresh-miss sc0sc1 loads; flag via ATOMIC fetch_add at
// the coherence point (stale-L2-proof poll). left/diag state in LDS fp32.
// Phase A: [64 b x 448 kp] = hq[64x224] @ W^T   (bf16 MFMA 16x16x32)
// Phase B: [64 b x 64 u]   = P [64x224] @ U2^T  (P = rr.*hu | x)

typedef short s16x8 __attribute__((ext_vector_type(8)));
typedef float f32x4 __attribute__((ext_vector_type(4)));

#define ASTR 232                 // hq row stride (bf16 elems); 224 data + 8 pad
#define N_WF (28*7*512)          // shorts
#define N_UF (4*7*512)           // shorts
#define N_XT (4096*1024)         // shorts
#define SMEM_BYTES (64*ASTR*2 + 3*64*68*4 + 2*64*68*4)   // 116736 B

#define HFv(s,b,u)  HF[(((s)*64 + (b))*68) + (u)]

__device__ __forceinline__ unsigned short f2bf(float v) {
    unsigned int x = __float_as_uint(v);
    unsigned int r = (x + 0x7fffu + ((x >> 16) & 1u)) >> 16;
    return (unsigned short)r;
}
__device__ __forceinline__ unsigned int pack2(float a, float b) {
    return (unsigned int)f2bf(a) | ((unsigned int)f2bf(b) << 16);
}

// ---- LLC write-through payload stores / fresh-miss payload loads ----
__device__ __forceinline__ void st_llc_f32(float* p, float v) {
    asm volatile("global_store_dword %0, %1, off sc0 sc1" :: "v"(p), "v"(v) : "memory");
}
__device__ __forceinline__ void ld_llc_row32(const float* p, f32x4& a, f32x4& b) {
    asm volatile("global_load_dwordx4 %0, %2, off sc0 sc1\n\t"
                 "global_load_dwordx4 %1, %3, off sc0 sc1\n\t"
                 "s_waitcnt vmcnt(0)"
                 : "=&v"(a), "=&v"(b) : "v"(p), "v"(p + 4) : "memory");
}

// ---- coherence-point flag ops (atomics cannot be served from stale L2) ----
__device__ __forceinline__ unsigned int poll_flag(unsigned int* p) {
    return __hip_atomic_fetch_add(p, 0u, __ATOMIC_RELAXED, __HIP_MEMORY_SCOPE_AGENT);
}
__device__ __forceinline__ void set_flag(unsigned int* p) {
    (void)__hip_atomic_fetch_add(p, 1u, __ATOMIC_RELAXED, __HIP_MEMORY_SCOPE_AGENT);
}

// ---- prep: pack weights into MFMA B-fragment lane order ----
__global__ __launch_bounds__(256) void prep_pack(
    const float* __restrict__ wr_w, const float* __restrict__ wr_b,
    const float* __restrict__ wz_w, const float* __restrict__ wz_b,
    const float* __restrict__ wij_w, const float* __restrict__ U_w,
    unsigned short* __restrict__ WF, unsigned short* __restrict__ UF,
    float* __restrict__ BAf)
{
    int idx = blockIdx.x * 256 + threadIdx.x;
    if (idx < 28*7*64) {
        int frag = idx >> 6, lane = idx & 63;
        int nt = frag / 7, ks = frag % 7;
        int kp = nt*16 + (lane & 15);
        int kb = ks*32 + ((lane >> 4) << 3);
        #pragma unroll
        for (int e = 0; e < 8; ++e) {
            int k = kb + e;
            float v = 0.f;
            if (k < 208) {
                if (kp < 192) v = wr_w[kp*208 + k];
                else { int q = kp - 192; v = wz_w[((q & 3)*64 + (q >> 2))*208 + k]; }
            }
            WF[idx*8 + e] = f2bf(v);
        }
        return;
    }
    idx -= 28*7*64;
    if (idx < 4*7*64) {
        int frag = idx >> 6, lane = idx & 63;
        int t2 = frag / 7, ks = frag % 7;
        int u = t2*16 + (lane & 15);
        int kb = ks*32 + ((lane >> 4) << 3);
        #pragma unroll
        for (int e = 0; e < 8; ++e) {
            int k = kb + e;
            float v = 0.f;
            if (k < 192) v = U_w[u*192 + k];
            else if (k < 208) v = wij_w[u*16 + (k - 192)];
            UF[idx*8 + e] = f2bf(v);
        }
        return;
    }
    idx -= 4*7*64;
    if (idx < 512) {
        float v = 0.f;
        if (idx < 192) v = wr_b[idx];
        else if (idx < 448) { int q = idx - 192; v = wz_b[(q & 3)*64 + (q >> 2)]; }
        BAf[idx] = v;
    }
}

// ---- prep: transpose inputs (B,C,L,R) -> XT[(l,r)][(b,c)] bf16 ----
__global__ __launch_bounds__(256) void xpose(const float* __restrict__ inp,
                                             unsigned short* __restrict__ XT)
{
    __shared__ float tile[32][33];
    int bi = blockIdx.x;   // lr / 32
    int bj = blockIdx.y;   // bc / 32
    int tx = threadIdx.x & 31, ty = threadIdx.x >> 5;
    #pragma unroll
    for (int yy = 0; yy < 4; ++yy) {
        int bc = bj*32 + ty*4 + yy;
        tile[ty*4 + yy][tx] = inp[bc*4096 + bi*32 + tx];
    }
    __syncthreads();
    #pragma unroll
    for (int yy = 0; yy < 4; ++yy) {
        int lr = bi*32 + ty*4 + yy;
        XT[lr*1024 + bj*32 + tx] = f2bf(tile[tx][ty*4 + yy]);
    }
}

// ---- persistent wavefront ----
__global__ __launch_bounds__(512, 2) void gru_persist(
    const unsigned short* __restrict__ WF,
    const unsigned short* __restrict__ UF,
    const float* __restrict__ BAf,
    const unsigned short* __restrict__ XT,
    const float* __restrict__ wij_b,
    float* __restrict__ Hout,          // [l][r][b][u] fp32
    unsigned int* __restrict__ flags,  // [l][r]
    float* __restrict__ out)
{
    extern __shared__ char smem[];
    unsigned short* hq_s = (unsigned short*)smem;            // [64][ASTR] bf16
    float* HF = (float*)(smem + 64*ASTR*2);                  // [3][64][68]: ht/hl/hd fp32
    float* ZH_s = HF + 3*64*68;                              // [64][68]
    float* ZI_s = ZH_s + 64*68;                              // [64][68]

    const int tid = threadIdx.x;
    // XCD-swizzle: dependency pairs (block b needs b-8) land on the same XCD
    const int l = ((blockIdx.x & 7) << 3) | (blockIdx.x >> 3);

    // init: HF zero; hq K-pad cols [208,232) zero
    for (int i = tid; i < 3*64*68; i += 512) HF[i] = 0.f;
    for (int i = tid; i < 64*24; i += 512) { int b = i/24, c = 208 + (i % 24); hq_s[b*ASTR + c] = 0; }

    const int wv = tid >> 6, lane = tid & 63;
    const int col = lane & 15, rowq = (lane >> 4) << 2;
    const int sb = tid >> 3, su = (tid & 7) * 8;             // staging ownership
    const int nh = wv & 3, mh = wv >> 2;                     // phase A tile
    const int mt = wv >> 1, th = (wv & 1) * 2;               // phase B tile

    for (int r = 0; r < 64; ++r) {
        // ---- staging part 1 (no top-row dependency): hd <- old ht; hl; x ----
        {
            float oht[8], hl8[8];
            #pragma unroll
            for (int e = 0; e < 8; ++e) oht[e] = HFv(0, sb, su + e);
            #pragma unroll
            for (int e = 0; e < 8; ++e) hl8[e] = HFv(1, sb, su + e);
            #pragma unroll
            for (int e = 0; e < 8; ++e) HFv(2, sb, su + e) = oht[e];
            #pragma unroll
            for (int e = 0; e < 8; e += 2) {
                *(unsigned int*)&hq_s[sb*ASTR +  64 + su + e] = pack2(hl8[e], hl8[e+1]); // hl
                *(unsigned int*)&hq_s[sb*ASTR + 128 + su + e] = pack2(oht[e], oht[e+1]); // hd
            }
            if (su < 16) {   // x: 2 threads per b row, 8 shorts each
                const unsigned short* xs = XT + ((size_t)(l*64 + r))*1024 + sb*16 + su;
                #pragma unroll
                for (int e = 0; e < 8; e += 2)
                    *(unsigned int*)&hq_s[sb*ASTR + 192 + su + e] = *(const unsigned int*)&xs[e];
            }
        }

        // ---- wait for top row (l-1, r): coherent atomic poll ----
        if (l > 0 && tid == 0) {
            while (poll_flag(&flags[(l-1)*64 + r]) == 0u)
                __builtin_amdgcn_s_sleep(1);
        }
        __syncthreads();

        // ---- staging part 2: ht <- row (l-1, r) via LLC loads ----
        {
            float nht[8];
            if (l > 0) {
                const float* Hrow = Hout + ((size_t)((l-1)*64 + r))*4096 + sb*64 + su;
                f32x4 a, b4;
                ld_llc_row32(Hrow, a, b4);
                nht[0]=a[0]; nht[1]=a[1]; nht[2]=a[2]; nht[3]=a[3];
                nht[4]=b4[0]; nht[5]=b4[1]; nht[6]=b4[2]; nht[7]=b4[3];
            } else {
                #pragma unroll
                for (int e = 0; e < 8; ++e) nht[e] = 0.f;
            }
            #pragma unroll
            for (int e = 0; e < 8; ++e) HFv(0, sb, su + e) = nht[e];
            #pragma unroll
            for (int e = 0; e < 8; e += 2)
                *(unsigned int*)&hq_s[sb*ASTR + su + e] = pack2(nht[e], nht[e+1]);       // ht
        }
        __syncthreads();

        // ---- phase A GEMM: 2 M-tiles x 7 N-tiles x 7 K ----
        f32x4 acc[7][2];
        #pragma unroll
        for (int t = 0; t < 7; ++t) { acc[t][0] = (f32x4){0,0,0,0}; acc[t][1] = (f32x4){0,0,0,0}; }
        #pragma unroll
        for (int ks = 0; ks < 7; ++ks) {
            s16x8 af0 = *(const s16x8*)&hq_s[(mh*32 + col)*ASTR + ks*32 + (rowq << 1)];
            s16x8 af1 = *(const s16x8*)&hq_s[(mh*32 + 16 + col)*ASTR + ks*32 + (rowq << 1)];
            #pragma unroll
            for (int t = 0; t < 7; ++t) {
                s16x8 bf = *(const s16x8*)&WF[(((nh*7 + t)*7 + ks)*64 + lane)*8];
                acc[t][0] = __builtin_amdgcn_mfma_f32_16x16x32_bf16(af0, bf, acc[t][0], 0, 0, 0);
                acc[t][1] = __builtin_amdgcn_mfma_f32_16x16x32_bf16(af1, bf, acc[t][1], 0, 0, 0);
            }
        }
        __syncthreads();

        // ---- activations: rr -> P (overwrite hq cols 0..191); z -> gates ----
        #pragma unroll
        for (int t = 0; t < 7; ++t) {
            const int kp = (nh*7 + t)*16 + col;
            const float bias = BAf[kp];
            const bool isrr = kp < 192;
            #pragma unroll
            for (int mti = 0; mti < 2; ++mti) {
                #pragma unroll
                for (int reg = 0; reg < 4; ++reg) {
                    const int b = (mh*2 + mti)*16 + rowq + reg;
                    const float val = acc[t][mti][reg] + bias;
                    if (isrr) {
                        float hu = (kp < 64)  ? HFv(1, b, kp)
                                 : (kp < 128) ? HFv(0, b, kp - 64)
                                              : HFv(2, b, kp - 128);
                        const float rr = 1.f / (1.f + __expf(-val));
                        hq_s[b*ASTR + kp] = f2bf(rr * hu);
                    } else {
                        const int g = lane & 3;
                        const int u = (kp - 192) >> 2;
                        float m = fmaxf(val, __shfl_xor(val, 1, 64));
                        m = fmaxf(m, __shfl_xor(m, 2, 64));
                        float e = __expf(val - m);
                        float s = e + __shfl_xor(e, 1, 64);
                        s += __shfl_xor(s, 2, 64);
                        const float gate = e / s;
                        float hsel = 0.f;
                        if (g == 1)      hsel = HFv(1, b, u);
                        else if (g == 2) hsel = HFv(0, b, u);
                        else if (g == 3) hsel = HFv(2, b, u);
                        float tt = gate * hsel;
                        float s3 = tt + __shfl_xor(tt, 1, 64);
                        s3 += __shfl_xor(s3, 2, 64);
                        if (g == 0) { ZI_s[b*68 + u] = gate; ZH_s[b*68 + u] = s3; }
                    }
                }
            }
        }
        __syncthreads();

        // ---- phase B GEMM + epilogue ----
        {
            f32x4 acc2[2];
            acc2[0] = (f32x4){0,0,0,0}; acc2[1] = (f32x4){0,0,0,0};
            #pragma unroll
            for (int ks = 0; ks < 7; ++ks) {
                s16x8 a2 = *(const s16x8*)&hq_s[(mt*16 + col)*ASTR + ks*32 + (rowq << 1)];
                #pragma unroll
                for (int i = 0; i < 2; ++i) {
                    s16x8 bf = *(const s16x8*)&UF[(((th + i)*7 + ks)*64 + lane)*8];
                    acc2[i] = __builtin_amdgcn_mfma_f32_16x16x32_bf16(a2, bf, acc2[i], 0, 0, 0);
                }
            }
            float* Hrow = Hout + ((size_t)(l*64 + r))*4096;
            #pragma unroll
            for (int i = 0; i < 2; ++i) {
                const int u = (th + i)*16 + col;
                const float wb = wij_b[u];
                #pragma unroll
                for (int reg = 0; reg < 4; ++reg) {
                    const int b = mt*16 + rowq + reg;
                    const float hn = tanhf(acc2[i][reg] + wb);
                    const float h = ZH_s[b*68 + u] + ZI_s[b*68 + u] * hn;
                    HFv(1, b, u) = h;                                   // hl for next step
                    if (l < 63) st_llc_f32(&Hrow[b*64 + u], h);         // write-through to LLC
                    else if (r == 63) out[b*64 + u] = h;
                }
            }
            // compiler's barrier waitcnt does NOT cover inline-asm stores:
            // drain them explicitly so the flag can't outrun the payload.
            asm volatile("s_waitcnt vmcnt(0)" ::: "memory");
        }
        __syncthreads();

        // ---- publish row (l, r): coherence-point atomic ----
        if (tid == 0 && l < 63)
            set_flag(&flags[l*64 + r]);
    }
}

extern "C" void kernel_launch(void* const* d_in, const int* in_sizes, int n_in,
                              void* d_out, int out_size, void* d_ws, size_t ws_size,
                              hipStream_t stream)
{
    const float* inp   = (const float*)d_in[0];
    const float* wr_w  = (const float*)d_in[1];
    const float* wr_b  = (const float*)d_in[2];
    const float* wz_w  = (const float*)d_in[3];
    const float* wz_b  = (const float*)d_in[4];
    const float* wij_w = (const float*)d_in[5];
    const float* wij_b = (const float*)d_in[6];
    const float* U_w   = (const float*)d_in[7];
    float* out = (float*)d_out;

    unsigned short* WF = (unsigned short*)d_ws;
    unsigned short* UF = WF + N_WF;
    unsigned short* XT = UF + N_UF;
    float* fbase = (float*)(XT + N_XT);
    float* BAf   = fbase;                          // 512 floats
    float* Hout  = fbase + 512;                    // 64*64*4096 floats (64 MB)
    unsigned int* flags = (unsigned int*)(Hout + (size_t)64*64*4096);  // 4096 ints

    hipMemsetAsync(flags, 0, 64*64*sizeof(unsigned int), stream);
    prep_pack<<<58, 256, 0, stream>>>(wr_w, wr_b, wz_w, wz_b, wij_w, U_w, WF, UF, BAf);
    xpose<<<dim3(128, 32), 256, 0, stream>>>(inp, XT);

    hipFuncSetAttribute((const void*)gru_persist,
                        hipFuncAttributeMaxDynamicSharedMemorySize, SMEM_BYTES);
    gru_persist<<<64, 512, SMEM_BYTES, stream>>>(WF, UF, BAf, XT, wij_b, Hout, flags, out);
}

// Round 6
// 3657.763 us; speedup vs baseline: 2.2274x; 2.2274x over previous
//
#include <hip/hip_runtime.h>
#include <math.h>

// SpatialGRU persistent-wavefront kernel. B=64, C=16, L=64, R=64, U=64, D=208.
// 64 persistent blocks, block = grid row l; cells (l, r=0..63) sequential.
// Round 6: CODE-SIZE restructure (I$-fit). Phase A is 14 rolled chunks of
// 32 outputs: tiny GEMM -> LDS scratch -> rolled activation (emitted once).
// Sync protocol identical to round 5 (atomic flag + sc0sc1 payload).
// Phase A: [64 b x 448 kp] = hq[64x224] @ W^T   (bf16 MFMA 16x16x32)
// Phase B: [64 b x 64 u]   = P [64x224] @ U2^T  (P = rr.*hu | x)

typedef short s16x8 __attribute__((ext_vector_type(8)));
typedef float f32x4 __attribute__((ext_vector_type(4)));

#define ASTR 232                 // hq/P row stride (bf16 elems); 224 data + 8 pad
#define N_WF (28*7*512)          // shorts
#define N_UF (4*7*512)           // shorts
#define N_XT (4096*1024)         // shorts

// LDS layout (bytes)
#define OFF_HQ 0                 // [64][ASTR] bf16 = 29696
#define OFF_P  29696             // [64][ASTR] bf16 = 29696
#define OFF_HF 59392             // [3][64][68] f32 = 52224
#define OFF_ZH 111616            // [64][68] f32 = 17408
#define OFF_ZI 129024            // [64][68] f32 = 17408
#define OFF_AS 146432            // [64][33] f32 = 8448
#define OFF_BA 154880            // [512] f32 = 2048
#define SMEM_BYTES 156928

#define HFv(s,b,u)  HF[(((s)*64 + (b))*68) + (u)]

__device__ __forceinline__ unsigned short f2bf(float v) {
    unsigned int x = __float_as_uint(v);
    unsigned int r = (x + 0x7fffu + ((x >> 16) & 1u)) >> 16;
    return (unsigned short)r;
}
__device__ __forceinline__ unsigned int pack2(float a, float b) {
    return (unsigned int)f2bf(a) | ((unsigned int)f2bf(b) << 16);
}

// ---- LLC write-through payload stores / fresh-miss payload loads ----
__device__ __forceinline__ void st_llc_f32(float* p, float v) {
    asm volatile("global_store_dword %0, %1, off sc0 sc1" :: "v"(p), "v"(v) : "memory");
}
__device__ __forceinline__ void ld_llc_row32(const float* p, f32x4& a, f32x4& b) {
    asm volatile("global_load_dwordx4 %0, %2, off sc0 sc1\n\t"
                 "global_load_dwordx4 %1, %3, off sc0 sc1\n\t"
                 "s_waitcnt vmcnt(0)"
                 : "=&v"(a), "=&v"(b) : "v"(p), "v"(p + 4) : "memory");
}

// ---- coherence-point flag ops ----
__device__ __forceinline__ unsigned int poll_flag(unsigned int* p) {
    return __hip_atomic_fetch_add(p, 0u, __ATOMIC_RELAXED, __HIP_MEMORY_SCOPE_AGENT);
}
__device__ __forceinline__ void set_flag(unsigned int* p) {
    (void)__hip_atomic_fetch_add(p, 1u, __ATOMIC_RELAXED, __HIP_MEMORY_SCOPE_AGENT);
}

// ---- prep: pack weights into MFMA B-fragment lane order ----
__global__ __launch_bounds__(256) void prep_pack(
    const float* __restrict__ wr_w, const float* __restrict__ wr_b,
    const float* __restrict__ wz_w, const float* __restrict__ wz_b,
    const float* __restrict__ wij_w, const float* __restrict__ U_w,
    unsigned short* __restrict__ WF, unsigned short* __restrict__ UF,
    float* __restrict__ BAf)
{
    int idx = blockIdx.x * 256 + threadIdx.x;
    if (idx < 28*7*64) {
        int frag = idx >> 6, lane = idx & 63;
        int nt = frag / 7, ks = frag % 7;
        int kp = nt*16 + (lane & 15);
        int kb = ks*32 + ((lane >> 4) << 3);
        #pragma unroll
        for (int e = 0; e < 8; ++e) {
            int k = kb + e;
            float v = 0.f;
            if (k < 208) {
                if (kp < 192) v = wr_w[kp*208 + k];
                else { int q = kp - 192; v = wz_w[((q & 3)*64 + (q >> 2))*208 + k]; }
            }
            WF[idx*8 + e] = f2bf(v);
        }
        return;
    }
    idx -= 28*7*64;
    if (idx < 4*7*64) {
        int frag = idx >> 6, lane = idx & 63;
        int t2 = frag / 7, ks = frag % 7;
        int u = t2*16 + (lane & 15);
        int kb = ks*32 + ((lane >> 4) << 3);
        #pragma unroll
        for (int e = 0; e < 8; ++e) {
            int k = kb + e;
            float v = 0.f;
            if (k < 192) v = U_w[u*192 + k];
            else if (k < 208) v = wij_w[u*16 + (k - 192)];
            UF[idx*8 + e] = f2bf(v);
        }
        return;
    }
    idx -= 4*7*64;
    if (idx < 512) {
        float v = 0.f;
        if (idx < 192) v = wr_b[idx];
        else if (idx < 448) { int q = idx - 192; v = wz_b[(q & 3)*64 + (q >> 2)]; }
        BAf[idx] = v;
    }
}

// ---- prep: transpose inputs (B,C,L,R) -> XT[(l,r)][(b,c)] bf16 ----
__global__ __launch_bounds__(256) void xpose(const float* __restrict__ inp,
                                             unsigned short* __restrict__ XT)
{
    __shared__ float tile[32][33];
    int bi = blockIdx.x;   // lr / 32
    int bj = blockIdx.y;   // bc / 32
    int tx = threadIdx.x & 31, ty = threadIdx.x >> 5;
    #pragma unroll
    for (int yy = 0; yy < 4; ++yy) {
        int bc = bj*32 + ty*4 + yy;
        tile[ty*4 + yy][tx] = inp[bc*4096 + bi*32 + tx];
    }
    __syncthreads();
    #pragma unroll
    for (int yy = 0; yy < 4; ++yy) {
        int lr = bi*32 + ty*4 + yy;
        XT[lr*1024 + bj*32 + tx] = f2bf(tile[tx][ty*4 + yy]);
    }
}

// ---- persistent wavefront ----
__global__ __launch_bounds__(512) void gru_persist(
    const unsigned short* __restrict__ WF,
    const unsigned short* __restrict__ UF,
    const float* __restrict__ BAf,
    const unsigned short* __restrict__ XT,
    const float* __restrict__ wij_b,
    float* __restrict__ Hout,          // [l][r][b][u] fp32
    unsigned int* __restrict__ flags,  // [l][r]
    float* __restrict__ out)
{
    extern __shared__ char smem[];
    unsigned short* hq_s = (unsigned short*)(smem + OFF_HQ);
    unsigned short* P_s  = (unsigned short*)(smem + OFF_P);
    float* HF   = (float*)(smem + OFF_HF);
    float* ZH_s = (float*)(smem + OFF_ZH);
    float* ZI_s = (float*)(smem + OFF_ZI);
    float* AS   = (float*)(smem + OFF_AS);
    float* BA_l = (float*)(smem + OFF_BA);

    const int tid = threadIdx.x;
    // XCD-swizzle: dependency pairs (l, l-1) land on the same XCD 7/8 of the time
    const int l = ((blockIdx.x & 7) << 3) | (blockIdx.x >> 3);

    // init: HF zero; hq/P K-pad cols [208,232) zero; bias to LDS
    for (int i = tid; i < 3*64*68; i += 512) HF[i] = 0.f;
    for (int i = tid; i < 64*24; i += 512) {
        int b = i/24, cc = 208 + (i % 24);
        hq_s[b*ASTR + cc] = 0; P_s[b*ASTR + cc] = 0;
    }
    BA_l[tid] = BAf[tid];
    __syncthreads();

    const int wv = tid >> 6, lane = tid & 63;
    const int col = lane & 15, rowq = (lane >> 4) << 2;
    const int sb = tid >> 3, su = (tid & 7) * 8;             // staging ownership
    const int mt4 = wv >> 1, ntl = wv & 1;                   // phase A chunk tile
    const int mt = wv >> 1, th = (wv & 1) * 2;               // phase B tile

    #pragma unroll 1
    for (int r = 0; r < 64; ++r) {
        // ---- staging part 1 (no top dependency): hd <- old ht; hl; x ----
        {
            float oht[8], hl8[8];
            #pragma unroll
            for (int e = 0; e < 8; ++e) oht[e] = HFv(0, sb, su + e);
            #pragma unroll
            for (int e = 0; e < 8; ++e) hl8[e] = HFv(1, sb, su + e);
            #pragma unroll
            for (int e = 0; e < 8; ++e) HFv(2, sb, su + e) = oht[e];
            #pragma unroll
            for (int e = 0; e < 8; e += 2) {
                *(unsigned int*)&hq_s[sb*ASTR +  64 + su + e] = pack2(hl8[e], hl8[e+1]); // hl
                *(unsigned int*)&hq_s[sb*ASTR + 128 + su + e] = pack2(oht[e], oht[e+1]); // hd
            }
            if (su < 16) {   // x tail -> both hq (phase A) and P (phase B)
                const unsigned short* xs = XT + ((size_t)(l*64 + r))*1024 + sb*16 + su;
                #pragma unroll
                for (int e = 0; e < 8; e += 2) {
                    unsigned int xv = *(const unsigned int*)&xs[e];
                    *(unsigned int*)&hq_s[sb*ASTR + 192 + su + e] = xv;
                    *(unsigned int*)&P_s [sb*ASTR + 192 + su + e] = xv;
                }
            }
        }

        // ---- wait for top row (l-1, r): coherent atomic poll ----
        if (l > 0 && tid == 0) {
            while (poll_flag(&flags[(l-1)*64 + r]) == 0u)
                __builtin_amdgcn_s_sleep(1);
        }
        __syncthreads();

        // ---- staging part 2: ht <- row (l-1, r) via LLC loads ----
        {
            float nht[8];
            if (l > 0) {
                const float* Hrow = Hout + ((size_t)((l-1)*64 + r))*4096 + sb*64 + su;
                f32x4 a, b4;
                ld_llc_row32(Hrow, a, b4);
                nht[0]=a[0]; nht[1]=a[1]; nht[2]=a[2]; nht[3]=a[3];
                nht[4]=b4[0]; nht[5]=b4[1]; nht[6]=b4[2]; nht[7]=b4[3];
            } else {
                #pragma unroll
                for (int e = 0; e < 8; ++e) nht[e] = 0.f;
            }
            #pragma unroll
            for (int e = 0; e < 8; ++e) HFv(0, sb, su + e) = nht[e];
            #pragma unroll
            for (int e = 0; e < 8; e += 2)
                *(unsigned int*)&hq_s[sb*ASTR + su + e] = pack2(nht[e], nht[e+1]);       // ht
        }
        __syncthreads();

        // ---- phase A: 14 chunks of 32 outputs (rolled; code emitted once) ----
        #pragma unroll 1
        for (int c = 0; c < 14; ++c) {
            // GEMM: wave (mt4, ntl): 16 b x 16 kp tile, K=224
            f32x4 acc = (f32x4){0.f, 0.f, 0.f, 0.f};
            #pragma unroll
            for (int ks = 0; ks < 7; ++ks) {
                s16x8 af = *(const s16x8*)&hq_s[(mt4*16 + col)*ASTR + ks*32 + (rowq << 1)];
                s16x8 bf = *(const s16x8*)&WF[(((c*2 + ntl)*7 + ks)*64 + lane)*8];
                acc = __builtin_amdgcn_mfma_f32_16x16x32_bf16(af, bf, acc, 0, 0, 0);
            }
            __syncthreads();   // previous chunk's activation done reading AS
            #pragma unroll
            for (int reg = 0; reg < 4; ++reg)
                AS[(mt4*16 + rowq + reg)*33 + ntl*16 + col] = acc[reg];
            __syncthreads();   // AS ready

            // activation: 4 values per thread, rolled
            const int kpl = tid & 31;
            const float bias = BA_l[c*32 + kpl];
            if (c < 6) {
                // rr chunks: c/2 -> {hl, ht, hd} = HF{1,0,2}
                const int sel = (c >= 4) ? 2 : (1 - (c >> 1));
                const float* Hsel = HF + sel*64*68;
                const int uoff = (c & 1)*32 + kpl;
                #pragma unroll 1
                for (int e = 0; e < 4; ++e) {
                    const int b = e*16 + (tid >> 5);
                    const float val = AS[b*33 + kpl] + bias;
                    const float rr = 1.f / (1.f + __expf(-val));
                    P_s[b*ASTR + c*32 + kpl] = f2bf(rr * Hsel[b*68 + uoff]);
                }
            } else {
                // z chunks: gate g = kpl&3 in quads [i,l,t,d]
                const int g = tid & 3;
                const int u = (c - 6)*8 + (kpl >> 2);
                #pragma unroll 1
                for (int e = 0; e < 4; ++e) {
                    const int b = e*16 + (tid >> 5);
                    const float val = AS[b*33 + kpl] + bias;
                    float m = fmaxf(val, __shfl_xor(val, 1, 64));
                    m = fmaxf(m, __shfl_xor(m, 2, 64));
                    const float ex = __expf(val - m);
                    float s = ex + __shfl_xor(ex, 1, 64);
                    s += __shfl_xor(s, 2, 64);
                    const float gate = ex / s;
                    float hsel = 0.f;
                    if (g == 1)      hsel = HFv(1, b, u);
                    else if (g == 2) hsel = HFv(0, b, u);
                    else if (g == 3) hsel = HFv(2, b, u);
                    float tt = gate * hsel;
                    float s3 = tt + __shfl_xor(tt, 1, 64);
                    s3 += __shfl_xor(s3, 2, 64);
                    if (g == 0) { ZI_s[b*68 + u] = gate; ZH_s[b*68 + u] = s3; }
                }
            }
        }
        __syncthreads();   // P, ZH, ZI complete

        // ---- phase B GEMM + epilogue ----
        {
            f32x4 acc2[2];
            acc2[0] = (f32x4){0,0,0,0}; acc2[1] = (f32x4){0,0,0,0};
            #pragma unroll
            for (int ks = 0; ks < 7; ++ks) {
                s16x8 a2 = *(const s16x8*)&P_s[(mt*16 + col)*ASTR + ks*32 + (rowq << 1)];
                #pragma unroll
                for (int i = 0; i < 2; ++i) {
                    s16x8 bf = *(const s16x8*)&UF[(((th + i)*7 + ks)*64 + lane)*8];
                    acc2[i] = __builtin_amdgcn_mfma_f32_16x16x32_bf16(a2, bf, acc2[i], 0, 0, 0);
                }
            }
            float* Hrow = Hout + ((size_t)(l*64 + r))*4096;
            #pragma unroll 1
            for (int i = 0; i < 2; ++i) {
                const int u = (th + i)*16 + col;
                const float wb = wij_b[u];
                #pragma unroll 1
                for (int reg = 0; reg < 4; ++reg) {
                    const int b = mt*16 + rowq + reg;
                    const float hn = tanhf(acc2[i][reg] + wb);
                    const float h = ZH_s[b*68 + u] + ZI_s[b*68 + u] * hn;
                    HFv(1, b, u) = h;                                   // hl for next step
                    if (l < 63) st_llc_f32(&Hrow[b*64 + u], h);         // write-through
                    else if (r == 63) out[b*64 + u] = h;
                }
            }
            // inline-asm stores are outside the compiler's barrier scoreboard:
            asm volatile("s_waitcnt vmcnt(0)" ::: "memory");
        }
        __syncthreads();

        // ---- publish row (l, r) ----
        if (tid == 0 && l < 63)
            set_flag(&flags[l*64 + r]);
    }
}

extern "C" void kernel_launch(void* const* d_in, const int* in_sizes, int n_in,
                              void* d_out, int out_size, void* d_ws, size_t ws_size,
                              hipStream_t stream)
{
    const float* inp   = (const float*)d_in[0];
    const float* wr_w  = (const float*)d_in[1];
    const float* wr_b  = (const float*)d_in[2];
    const float* wz_w  = (const float*)d_in[3];
    const float* wz_b  = (const float*)d_in[4];
    const float* wij_w = (const float*)d_in[5];
    const float* wij_b = (const float*)d_in[6];
    const float* U_w   = (const float*)d_in[7];
    float* out = (float*)d_out;

    unsigned short* WF = (unsigned short*)d_ws;
    unsigned short* UF = WF + N_WF;
    unsigned short* XT = UF + N_UF;
    float* fbase = (float*)(XT + N_XT);
    float* BAf   = fbase;                          // 512 floats
    float* Hout  = fbase + 512;                    // 64*64*4096 floats (64 MB)
    unsigned int* flags = (unsigned int*)(Hout + (size_t)64*64*4096);  // 4096 ints

    hipMemsetAsync(flags, 0, 64*64*sizeof(unsigned int), stream);
    prep_pack<<<58, 256, 0, stream>>>(wr_w, wr_b, wz_w, wz_b, wij_w, U_w, WF, UF, BAf);
    xpose<<<dim3(128, 32), 256, 0, stream>>>(inp, XT);

    hipFuncSetAttribute((const void*)gru_persist,
                        hipFuncAttributeMaxDynamicSharedMemorySize, SMEM_BYTES);
    gru_persist<<<64, 512, SMEM_BYTES, stream>>>(WF, UF, BAf, XT, wij_b, Hout, flags, out);
}

// Round 7
// 2466.986 us; speedup vs baseline: 3.3025x; 1.4827x over previous
//
#include <hip/hip_runtime.h>
#include <math.h>

// SpatialGRU persistent-wavefront kernel. B=64, C=16, L=64, R=64, U=64, D=208.
// 64 persistent blocks, block = grid row l; cells (l, r=0..63) sequential.
// Round 7: WEIGHT-STATIONARY registers (loaded once, zero per-step weight
// traffic) + IN-REGISTER activation on MFMA acc (no AS tile, 4 barriers/step).
// Sync: atomic flag + sc0sc1 write-through payload (unchanged since r5).
// Phase A: [64 b x 448 kp] = hq[64x224] @ W^T   (bf16 MFMA 16x16x32)
// Phase B: [64 b x 64 u]   = P [64x224] @ U2^T  (P = rr.*hu | x)

typedef short s16x8 __attribute__((ext_vector_type(8)));
typedef float f32x4 __attribute__((ext_vector_type(4)));

#define ASTR 232                 // hq/P row stride (bf16 elems); 224 data + 8 pad
#define N_WF (32*7*512)          // shorts (32 N-tiles: 28 real + 4 zero pad)
#define N_UF (4*7*512)           // shorts
#define N_XT (4096*1024)         // shorts

// LDS layout (bytes)
#define OFF_HQ 0                 // [64][ASTR] bf16 = 29696
#define OFF_P  29696             // [64][ASTR] bf16 = 29696
#define OFF_HF 59392             // [3][64][68] f32 = 52224
#define OFF_ZH 111616            // [64][68] f32 = 17408
#define OFF_ZI 129024            // [64][68] f32 = 17408
#define OFF_BA 146432            // [512] f32 = 2048
#define SMEM_BYTES 148480

#define HFv(s,b,u)  HF[(((s)*64 + (b))*68) + (u)]

__device__ __forceinline__ unsigned short f2bf(float v) {
    unsigned int x = __float_as_uint(v);
    unsigned int r = (x + 0x7fffu + ((x >> 16) & 1u)) >> 16;
    return (unsigned short)r;
}
__device__ __forceinline__ unsigned int pack2(float a, float b) {
    return (unsigned int)f2bf(a) | ((unsigned int)f2bf(b) << 16);
}

// ---- LLC write-through payload stores / fresh-miss payload loads ----
__device__ __forceinline__ void st_llc_f32(float* p, float v) {
    asm volatile("global_store_dword %0, %1, off sc0 sc1" :: "v"(p), "v"(v) : "memory");
}
__device__ __forceinline__ void ld_llc_row32(const float* p, f32x4& a, f32x4& b) {
    asm volatile("global_load_dwordx4 %0, %2, off sc0 sc1\n\t"
                 "global_load_dwordx4 %1, %3, off sc0 sc1\n\t"
                 "s_waitcnt vmcnt(0)"
                 : "=&v"(a), "=&v"(b) : "v"(p), "v"(p + 4) : "memory");
}

// ---- coherence-point flag ops ----
__device__ __forceinline__ unsigned int poll_flag(unsigned int* p) {
    return __hip_atomic_fetch_add(p, 0u, __ATOMIC_RELAXED, __HIP_MEMORY_SCOPE_AGENT);
}
__device__ __forceinline__ void set_flag(unsigned int* p) {
    (void)__hip_atomic_fetch_add(p, 1u, __ATOMIC_RELAXED, __HIP_MEMORY_SCOPE_AGENT);
}

// ---- prep: pack weights into MFMA B-fragment lane order ----
__global__ __launch_bounds__(256) void prep_pack(
    const float* __restrict__ wr_w, const float* __restrict__ wr_b,
    const float* __restrict__ wz_w, const float* __restrict__ wz_b,
    const float* __restrict__ wij_w, const float* __restrict__ U_w,
    unsigned short* __restrict__ WF, unsigned short* __restrict__ UF,
    float* __restrict__ BAf)
{
    int idx = blockIdx.x * 256 + threadIdx.x;
    if (idx < 32*7*64) {
        int frag = idx >> 6, lane = idx & 63;
        int nt = frag / 7, ks = frag % 7;
        int kp = nt*16 + (lane & 15);
        int kb = ks*32 + ((lane >> 4) << 3);
        #pragma unroll
        for (int e = 0; e < 8; ++e) {
            int k = kb + e;
            float v = 0.f;
            if (k < 208) {
                if (kp < 192) v = wr_w[kp*208 + k];
                else if (kp < 448) { int q = kp - 192; v = wz_w[((q & 3)*64 + (q >> 2))*208 + k]; }
            }
            WF[idx*8 + e] = f2bf(v);
        }
        return;
    }
    idx -= 32*7*64;
    if (idx < 4*7*64) {
        int frag = idx >> 6, lane = idx & 63;
        int t2 = frag / 7, ks = frag % 7;
        int u = t2*16 + (lane & 15);
        int kb = ks*32 + ((lane >> 4) << 3);
        #pragma unroll
        for (int e = 0; e < 8; ++e) {
            int k = kb + e;
            float v = 0.f;
            if (k < 192) v = U_w[u*192 + k];
            else if (k < 208) v = wij_w[u*16 + (k - 192)];
            UF[idx*8 + e] = f2bf(v);
        }
        return;
    }
    idx -= 4*7*64;
    if (idx < 512) {
        float v = 0.f;
        if (idx < 192) v = wr_b[idx];
        else if (idx < 448) { int q = idx - 192; v = wz_b[(q & 3)*64 + (q >> 2)]; }
        BAf[idx] = v;
    }
}

// ---- prep: transpose inputs (B,C,L,R) -> XT[(l,r)][(b,c)] bf16 ----
__global__ __launch_bounds__(256) void xpose(const float* __restrict__ inp,
                                             unsigned short* __restrict__ XT)
{
    __shared__ float tile[32][33];
    int bi = blockIdx.x;   // lr / 32
    int bj = blockIdx.y;   // bc / 32
    int tx = threadIdx.x & 31, ty = threadIdx.x >> 5;
    #pragma unroll
    for (int yy = 0; yy < 4; ++yy) {
        int bc = bj*32 + ty*4 + yy;
        tile[ty*4 + yy][tx] = inp[bc*4096 + bi*32 + tx];
    }
    __syncthreads();
    #pragma unroll
    for (int yy = 0; yy < 4; ++yy) {
        int lr = bi*32 + ty*4 + yy;
        XT[lr*1024 + bj*32 + tx] = f2bf(tile[tx][ty*4 + yy]);
    }
}

// ---- persistent wavefront ----
__global__ __launch_bounds__(512) void gru_persist(
    const unsigned short* __restrict__ WF,
    const unsigned short* __restrict__ UF,
    const float* __restrict__ BAf,
    const unsigned short* __restrict__ XT,
    const float* __restrict__ wij_b,
    float* __restrict__ Hout,          // [l][r][b][u] fp32
    unsigned int* __restrict__ flags,  // [l][r]
    float* __restrict__ out)
{
    extern __shared__ char smem[];
    unsigned short* hq_s = (unsigned short*)(smem + OFF_HQ);
    unsigned short* P_s  = (unsigned short*)(smem + OFF_P);
    float* HF   = (float*)(smem + OFF_HF);
    float* ZH_s = (float*)(smem + OFF_ZH);
    float* ZI_s = (float*)(smem + OFF_ZI);
    float* BA_l = (float*)(smem + OFF_BA);

    const int tid = threadIdx.x;
    // XCD-swizzle: dependency pairs (l, l-1) land on the same XCD 7/8 of the time
    const int l = ((blockIdx.x & 7) << 3) | (blockIdx.x >> 3);

    // init: HF zero; hq/P K-pad cols [208,232) zero; bias to LDS
    for (int i = tid; i < 3*64*68; i += 512) HF[i] = 0.f;
    for (int i = tid; i < 64*24; i += 512) {
        int b = i/24, cc = 208 + (i % 24);
        hq_s[b*ASTR + cc] = 0; P_s[b*ASTR + cc] = 0;
    }
    BA_l[tid] = BAf[tid];

    const int wv = tid >> 6, lane = tid & 63;
    const int col = lane & 15, rowq = (lane >> 4) << 2;
    const int sb = tid >> 3, su = (tid & 7) * 8;             // staging ownership
    const int nB = wv >> 1, mhB = wv & 1;                    // phase B tile

    // ---- load weights into registers ONCE (stationary for all 64 steps) ----
    s16x8 wa[4][7];
    #pragma unroll
    for (int j = 0; j < 4; ++j)
        #pragma unroll
        for (int ks = 0; ks < 7; ++ks)
            wa[j][ks] = *(const s16x8*)&WF[(((wv + 8*j)*7 + ks)*64 + lane)*8];
    s16x8 ub[7];
    #pragma unroll
    for (int ks = 0; ks < 7; ++ks)
        ub[ks] = *(const s16x8*)&UF[((nB*7 + ks)*64 + lane)*8];
    __syncthreads();

    #pragma unroll 1
    for (int r = 0; r < 64; ++r) {
        // ---- staging part 1 (no top dependency): hd <- old ht; hl; x ----
        {
            float oht[8], hl8[8];
            #pragma unroll
            for (int e = 0; e < 8; ++e) oht[e] = HFv(0, sb, su + e);
            #pragma unroll
            for (int e = 0; e < 8; ++e) hl8[e] = HFv(1, sb, su + e);
            #pragma unroll
            for (int e = 0; e < 8; ++e) HFv(2, sb, su + e) = oht[e];
            #pragma unroll
            for (int e = 0; e < 8; e += 2) {
                *(unsigned int*)&hq_s[sb*ASTR +  64 + su + e] = pack2(hl8[e], hl8[e+1]); // hl
                *(unsigned int*)&hq_s[sb*ASTR + 128 + su + e] = pack2(oht[e], oht[e+1]); // hd
            }
            if (su < 16) {   // x tail -> both hq (phase A) and P (phase B)
                const unsigned short* xs = XT + ((size_t)(l*64 + r))*1024 + sb*16 + su;
                #pragma unroll
                for (int e = 0; e < 8; e += 2) {
                    unsigned int xv = *(const unsigned int*)&xs[e];
                    *(unsigned int*)&hq_s[sb*ASTR + 192 + su + e] = xv;
                    *(unsigned int*)&P_s [sb*ASTR + 192 + su + e] = xv;
                }
            }
        }

        // ---- wait for top row (l-1, r): coherent atomic poll ----
        if (l > 0 && tid == 0) {
            while (poll_flag(&flags[(l-1)*64 + r]) == 0u)
                __builtin_amdgcn_s_sleep(2);
        }
        __syncthreads();

        // ---- staging part 2: ht <- row (l-1, r) via LLC loads ----
        {
            float nht[8];
            if (l > 0) {
                const float* Hrow = Hout + ((size_t)((l-1)*64 + r))*4096 + sb*64 + su;
                f32x4 a, b4;
                ld_llc_row32(Hrow, a, b4);
                nht[0]=a[0]; nht[1]=a[1]; nht[2]=a[2]; nht[3]=a[3];
                nht[4]=b4[0]; nht[5]=b4[1]; nht[6]=b4[2]; nht[7]=b4[3];
            } else {
                #pragma unroll
                for (int e = 0; e < 8; ++e) nht[e] = 0.f;
            }
            #pragma unroll
            for (int e = 0; e < 8; ++e) HFv(0, sb, su + e) = nht[e];
            #pragma unroll
            for (int e = 0; e < 8; e += 2)
                *(unsigned int*)&hq_s[sb*ASTR + su + e] = pack2(nht[e], nht[e+1]);       // ht
        }
        __syncthreads();

        // ---- phase A: 4 m-tiles; MFMA from registers, activation on acc ----
        #pragma unroll 1
        for (int m = 0; m < 4; ++m) {
            f32x4 acc[4];
            #pragma unroll
            for (int j = 0; j < 4; ++j) acc[j] = (f32x4){0.f, 0.f, 0.f, 0.f};
            #pragma unroll
            for (int ks = 0; ks < 7; ++ks) {
                s16x8 af = *(const s16x8*)&hq_s[(m*16 + col)*ASTR + ks*32 + (rowq << 1)];
                #pragma unroll
                for (int j = 0; j < 4; ++j)
                    acc[j] = __builtin_amdgcn_mfma_f32_16x16x32_bf16(af, wa[j][ks], acc[j], 0, 0, 0);
            }
            // in-register activation (wave-uniform branch per j)
            #pragma unroll
            for (int j = 0; j < 4; ++j) {
                const int nt = wv + 8*j;
                const int kp = nt*16 + col;
                const float bias = BA_l[kp];
                if (nt < 12) {
                    // rr: P[b][kp] = sigmoid(val) * hu[kp]; hu = [hl|ht|hd] = HF{1,0,2}
                    const int sel = (nt >> 2);
                    const float* Hsel = HF + ((sel == 0) ? 1 : (sel == 1) ? 0 : 2)*64*68;
                    const int uoff = (nt & 3)*16 + col;
                    #pragma unroll
                    for (int reg = 0; reg < 4; ++reg) {
                        const int b = m*16 + rowq + reg;
                        const float val = acc[j][reg] + bias;
                        const float rr = 1.f / (1.f + __expf(-val));
                        P_s[b*ASTR + kp] = f2bf(rr * Hsel[b*68 + uoff]);
                    }
                } else if (nt < 28) {
                    // z: gate g = col&3 in quads [i,l,t,d]; softmax via shfl
                    const int g = col & 3;
                    const int u = (nt - 12)*4 + (col >> 2);
                    #pragma unroll
                    for (int reg = 0; reg < 4; ++reg) {
                        const int b = m*16 + rowq + reg;
                        const float val = acc[j][reg] + bias;
                        float mx = fmaxf(val, __shfl_xor(val, 1, 64));
                        mx = fmaxf(mx, __shfl_xor(mx, 2, 64));
                        const float ex = __expf(val - mx);
                        float s = ex + __shfl_xor(ex, 1, 64);
                        s += __shfl_xor(s, 2, 64);
                        const float gate = ex / s;
                        float hsel = 0.f;
                        if (g == 1)      hsel = HFv(1, b, u);
                        else if (g == 2) hsel = HFv(0, b, u);
                        else if (g == 3) hsel = HFv(2, b, u);
                        float tt = gate * hsel;
                        float s3 = tt + __shfl_xor(tt, 1, 64);
                        s3 += __shfl_xor(s3, 2, 64);
                        if (g == 0) { ZI_s[b*68 + u] = gate; ZH_s[b*68 + u] = s3; }
                    }
                }
                // nt >= 28: zero-pad tile, no output
            }
        }
        __syncthreads();   // P, ZH, ZI complete

        // ---- phase B GEMM (weights in regs) + epilogue ----
        {
            f32x4 acc2[2];
            acc2[0] = (f32x4){0,0,0,0}; acc2[1] = (f32x4){0,0,0,0};
            #pragma unroll
            for (int ks = 0; ks < 7; ++ks) {
                #pragma unroll
                for (int mi = 0; mi < 2; ++mi) {
                    s16x8 a2 = *(const s16x8*)&P_s[((mhB*2 + mi)*16 + col)*ASTR + ks*32 + (rowq << 1)];
                    acc2[mi] = __builtin_amdgcn_mfma_f32_16x16x32_bf16(a2, ub[ks], acc2[mi], 0, 0, 0);
                }
            }
            float* Hrow = Hout + ((size_t)(l*64 + r))*4096;
            const int u = nB*16 + col;
            const float wb = wij_b[u];
            #pragma unroll 1
            for (int mi = 0; mi < 2; ++mi) {
                #pragma unroll 1
                for (int reg = 0; reg < 4; ++reg) {
                    const int b = (mhB*2 + mi)*16 + rowq + reg;
                    const float hn = tanhf(acc2[mi][reg] + wb);
                    const float h = ZH_s[b*68 + u] + ZI_s[b*68 + u] * hn;
                    HFv(1, b, u) = h;                                   // hl for next step
                    if (l < 63) st_llc_f32(&Hrow[b*64 + u], h);         // write-through
                    else if (r == 63) out[b*64 + u] = h;
                }
            }
            // inline-asm stores are outside the compiler's barrier scoreboard:
            asm volatile("s_waitcnt vmcnt(0)" ::: "memory");
        }
        __syncthreads();

        // ---- publish row (l, r) ----
        if (tid == 0 && l < 63)
            set_flag(&flags[l*64 + r]);
    }
}

extern "C" void kernel_launch(void* const* d_in, const int* in_sizes, int n_in,
                              void* d_out, int out_size, void* d_ws, size_t ws_size,
                              hipStream_t stream)
{
    const float* inp   = (const float*)d_in[0];
    const float* wr_w  = (const float*)d_in[1];
    const float* wr_b  = (const float*)d_in[2];
    const float* wz_w  = (const float*)d_in[3];
    const float* wz_b  = (const float*)d_in[4];
    const float* wij_w = (const float*)d_in[5];
    const float* wij_b = (const float*)d_in[6];
    const float* U_w   = (const float*)d_in[7];
    float* out = (float*)d_out;

    unsigned short* WF = (unsigned short*)d_ws;
    unsigned short* UF = WF + N_WF;
    unsigned short* XT = UF + N_UF;
    float* fbase = (float*)(XT + N_XT);
    float* BAf   = fbase;                          // 512 floats
    float* Hout  = fbase + 512;                    // 64*64*4096 floats (64 MB)
    unsigned int* flags = (unsigned int*)(Hout + (size_t)64*64*4096);  // 4096 ints

    hipMemsetAsync(flags, 0, 64*64*sizeof(unsigned int), stream);
    prep_pack<<<66, 256, 0, stream>>>(wr_w, wr_b, wz_w, wz_b, wij_w, U_w, WF, UF, BAf);
    xpose<<<dim3(128, 32), 256, 0, stream>>>(inp, XT);

    hipFuncSetAttribute((const void*)gru_persist,
                        hipFuncAttributeMaxDynamicSharedMemorySize, SMEM_BYTES);
    gru_persist<<<64, 512, SMEM_BYTES, stream>>>(WF, UF, BAf, XT, wij_b, Hout, flags, out);
}

// Round 8
// 2419.365 us; speedup vs baseline: 3.3675x; 1.0197x over previous
//
#include <hip/hip_runtime.h>
#include <math.h>

// SpatialGRU persistent-wavefront kernel. B=64, C=16, L=64, R=64, U=64, D=208.
// 64 persistent blocks, block = grid row l; cells (l, r=0..63) sequential.
// Round 8: FORCE weight-stationarity: __launch_bounds__(512,2) (256-VGPR
// budget) + asm-pin of weight fragments (no rematerialization). Fast tanh.
// Sync: atomic flag + sc0sc1 write-through payload (unchanged since r5).
// Phase A: [64 b x 448 kp] = hq[64x224] @ W^T   (bf16 MFMA 16x16x32)
// Phase B: [64 b x 64 u]   = P [64x224] @ U2^T  (P = rr.*hu | x)

typedef short s16x8 __attribute__((ext_vector_type(8)));
typedef float f32x4 __attribute__((ext_vector_type(4)));

#define ASTR 232                 // hq/P row stride (bf16 elems); 224 data + 8 pad
#define N_WF (32*7*512)          // shorts (32 N-tiles: 28 real + 4 zero pad)
#define N_UF (4*7*512)           // shorts
#define N_XT (4096*1024)         // shorts

// LDS layout (bytes)
#define OFF_HQ 0                 // [64][ASTR] bf16 = 29696
#define OFF_P  29696             // [64][ASTR] bf16 = 29696
#define OFF_HF 59392             // [3][64][68] f32 = 52224
#define OFF_ZH 111616            // [64][68] f32 = 17408
#define OFF_ZI 129024            // [64][68] f32 = 17408
#define OFF_BA 146432            // [512] f32 = 2048
#define SMEM_BYTES 148480

#define HFv(s,b,u)  HF[(((s)*64 + (b))*68) + (u)]

__device__ __forceinline__ unsigned short f2bf(float v) {
    unsigned int x = __float_as_uint(v);
    unsigned int r = (x + 0x7fffu + ((x >> 16) & 1u)) >> 16;
    return (unsigned short)r;
}
__device__ __forceinline__ unsigned int pack2(float a, float b) {
    return (unsigned int)f2bf(a) | ((unsigned int)f2bf(b) << 16);
}
__device__ __forceinline__ float tanh_fast(float x) {
    x = fminf(fmaxf(x, -15.f), 15.f);
    const float e = __expf(2.f * x);
    return (e - 1.f) / (e + 1.f);
}

// ---- LLC write-through payload stores / fresh-miss payload loads ----
__device__ __forceinline__ void st_llc_f32(float* p, float v) {
    asm volatile("global_store_dword %0, %1, off sc0 sc1" :: "v"(p), "v"(v) : "memory");
}
__device__ __forceinline__ void ld_llc_row32(const float* p, f32x4& a, f32x4& b) {
    asm volatile("global_load_dwordx4 %0, %2, off sc0 sc1\n\t"
                 "global_load_dwordx4 %1, %3, off sc0 sc1\n\t"
                 "s_waitcnt vmcnt(0)"
                 : "=&v"(a), "=&v"(b) : "v"(p), "v"(p + 4) : "memory");
}

// ---- coherence-point flag ops ----
__device__ __forceinline__ unsigned int poll_flag(unsigned int* p) {
    return __hip_atomic_fetch_add(p, 0u, __ATOMIC_RELAXED, __HIP_MEMORY_SCOPE_AGENT);
}
__device__ __forceinline__ void set_flag(unsigned int* p) {
    (void)__hip_atomic_fetch_add(p, 1u, __ATOMIC_RELAXED, __HIP_MEMORY_SCOPE_AGENT);
}

// ---- prep: pack weights into MFMA B-fragment lane order ----
__global__ __launch_bounds__(256) void prep_pack(
    const float* __restrict__ wr_w, const float* __restrict__ wr_b,
    const float* __restrict__ wz_w, const float* __restrict__ wz_b,
    const float* __restrict__ wij_w, const float* __restrict__ U_w,
    unsigned short* __restrict__ WF, unsigned short* __restrict__ UF,
    float* __restrict__ BAf)
{
    int idx = blockIdx.x * 256 + threadIdx.x;
    if (idx < 32*7*64) {
        int frag = idx >> 6, lane = idx & 63;
        int nt = frag / 7, ks = frag % 7;
        int kp = nt*16 + (lane & 15);
        int kb = ks*32 + ((lane >> 4) << 3);
        #pragma unroll
        for (int e = 0; e < 8; ++e) {
            int k = kb + e;
            float v = 0.f;
            if (k < 208) {
                if (kp < 192) v = wr_w[kp*208 + k];
                else if (kp < 448) { int q = kp - 192; v = wz_w[((q & 3)*64 + (q >> 2))*208 + k]; }
            }
            WF[idx*8 + e] = f2bf(v);
        }
        return;
    }
    idx -= 32*7*64;
    if (idx < 4*7*64) {
        int frag = idx >> 6, lane = idx & 63;
        int t2 = frag / 7, ks = frag % 7;
        int u = t2*16 + (lane & 15);
        int kb = ks*32 + ((lane >> 4) << 3);
        #pragma unroll
        for (int e = 0; e < 8; ++e) {
            int k = kb + e;
            float v = 0.f;
            if (k < 192) v = U_w[u*192 + k];
            else if (k < 208) v = wij_w[u*16 + (k - 192)];
            UF[idx*8 + e] = f2bf(v);
        }
        return;
    }
    idx -= 4*7*64;
    if (idx < 512) {
        float v = 0.f;
        if (idx < 192) v = wr_b[idx];
        else if (idx < 448) { int q = idx - 192; v = wz_b[(q & 3)*64 + (q >> 2)]; }
        BAf[idx] = v;
    }
}

// ---- prep: transpose inputs (B,C,L,R) -> XT[(l,r)][(b,c)] bf16 ----
__global__ __launch_bounds__(256) void xpose(const float* __restrict__ inp,
                                             unsigned short* __restrict__ XT)
{
    __shared__ float tile[32][33];
    int bi = blockIdx.x;   // lr / 32
    int bj = blockIdx.y;   // bc / 32
    int tx = threadIdx.x & 31, ty = threadIdx.x >> 5;
    #pragma unroll
    for (int yy = 0; yy < 4; ++yy) {
        int bc = bj*32 + ty*4 + yy;
        tile[ty*4 + yy][tx] = inp[bc*4096 + bi*32 + tx];
    }
    __syncthreads();
    #pragma unroll
    for (int yy = 0; yy < 4; ++yy) {
        int lr = bi*32 + ty*4 + yy;
        XT[lr*1024 + bj*32 + tx] = f2bf(tile[tx][ty*4 + yy]);
    }
}

// ---- persistent wavefront ----
__global__ __launch_bounds__(512, 2) void gru_persist(
    const unsigned short* __restrict__ WF,
    const unsigned short* __restrict__ UF,
    const float* __restrict__ BAf,
    const unsigned short* __restrict__ XT,
    const float* __restrict__ wij_b,
    float* __restrict__ Hout,          // [l][r][b][u] fp32
    unsigned int* __restrict__ flags,  // [l][r]
    float* __restrict__ out)
{
    extern __shared__ char smem[];
    unsigned short* hq_s = (unsigned short*)(smem + OFF_HQ);
    unsigned short* P_s  = (unsigned short*)(smem + OFF_P);
    float* HF   = (float*)(smem + OFF_HF);
    float* ZH_s = (float*)(smem + OFF_ZH);
    float* ZI_s = (float*)(smem + OFF_ZI);
    float* BA_l = (float*)(smem + OFF_BA);

    const int tid = threadIdx.x;
    // XCD-swizzle: dependency pairs (l, l-1) land on the same XCD 7/8 of the time
    const int l = ((blockIdx.x & 7) << 3) | (blockIdx.x >> 3);

    // init: HF zero; hq/P K-pad cols [208,232) zero; bias to LDS
    for (int i = tid; i < 3*64*68; i += 512) HF[i] = 0.f;
    for (int i = tid; i < 64*24; i += 512) {
        int b = i/24, cc = 208 + (i % 24);
        hq_s[b*ASTR + cc] = 0; P_s[b*ASTR + cc] = 0;
    }
    BA_l[tid] = BAf[tid];

    const int wv = tid >> 6, lane = tid & 63;
    const int col = lane & 15, rowq = (lane >> 4) << 2;
    const int sb = tid >> 3, su = (tid & 7) * 8;             // staging ownership
    const int nB = wv >> 1, mhB = wv & 1;                    // phase B tile

    // ---- load weights into registers ONCE; asm-pin against remat ----
    s16x8 wa[4][7];
    #pragma unroll
    for (int j = 0; j < 4; ++j)
        #pragma unroll
        for (int ks = 0; ks < 7; ++ks) {
            wa[j][ks] = *(const s16x8*)&WF[(((wv + 8*j)*7 + ks)*64 + lane)*8];
            asm volatile("" : "+v"(wa[j][ks]));
        }
    s16x8 ub[7];
    #pragma unroll
    for (int ks = 0; ks < 7; ++ks) {
        ub[ks] = *(const s16x8*)&UF[((nB*7 + ks)*64 + lane)*8];
        asm volatile("" : "+v"(ub[ks]));
    }
    __syncthreads();

    #pragma unroll 1
    for (int r = 0; r < 64; ++r) {
        // ---- staging part 1 (no top dependency): hd <- old ht; hl; x ----
        {
            float oht[8], hl8[8];
            #pragma unroll
            for (int e = 0; e < 8; ++e) oht[e] = HFv(0, sb, su + e);
            #pragma unroll
            for (int e = 0; e < 8; ++e) hl8[e] = HFv(1, sb, su + e);
            #pragma unroll
            for (int e = 0; e < 8; ++e) HFv(2, sb, su + e) = oht[e];
            #pragma unroll
            for (int e = 0; e < 8; e += 2) {
                *(unsigned int*)&hq_s[sb*ASTR +  64 + su + e] = pack2(hl8[e], hl8[e+1]); // hl
                *(unsigned int*)&hq_s[sb*ASTR + 128 + su + e] = pack2(oht[e], oht[e+1]); // hd
            }
            if (su < 16) {   // x tail -> both hq (phase A) and P (phase B)
                const unsigned short* xs = XT + ((size_t)(l*64 + r))*1024 + sb*16 + su;
                #pragma unroll
                for (int e = 0; e < 8; e += 2) {
                    unsigned int xv = *(const unsigned int*)&xs[e];
                    *(unsigned int*)&hq_s[sb*ASTR + 192 + su + e] = xv;
                    *(unsigned int*)&P_s [sb*ASTR + 192 + su + e] = xv;
                }
            }
        }

        // ---- wait for top row (l-1, r): coherent atomic poll ----
        if (l > 0 && tid == 0) {
            while (poll_flag(&flags[(l-1)*64 + r]) == 0u)
                __builtin_amdgcn_s_sleep(1);
        }
        __syncthreads();

        // ---- staging part 2: ht <- row (l-1, r) via LLC loads ----
        {
            float nht[8];
            if (l > 0) {
                const float* Hrow = Hout + ((size_t)((l-1)*64 + r))*4096 + sb*64 + su;
                f32x4 a, b4;
                ld_llc_row32(Hrow, a, b4);
                nht[0]=a[0]; nht[1]=a[1]; nht[2]=a[2]; nht[3]=a[3];
                nht[4]=b4[0]; nht[5]=b4[1]; nht[6]=b4[2]; nht[7]=b4[3];
            } else {
                #pragma unroll
                for (int e = 0; e < 8; ++e) nht[e] = 0.f;
            }
            #pragma unroll
            for (int e = 0; e < 8; ++e) HFv(0, sb, su + e) = nht[e];
            #pragma unroll
            for (int e = 0; e < 8; e += 2)
                *(unsigned int*)&hq_s[sb*ASTR + su + e] = pack2(nht[e], nht[e+1]);       // ht
        }
        __syncthreads();

        // ---- phase A: 4 m-tiles; MFMA from registers, activation on acc ----
        #pragma unroll 1
        for (int m = 0; m < 4; ++m) {
            f32x4 acc[4];
            #pragma unroll
            for (int j = 0; j < 4; ++j) acc[j] = (f32x4){0.f, 0.f, 0.f, 0.f};
            #pragma unroll
            for (int ks = 0; ks < 7; ++ks) {
                s16x8 af = *(const s16x8*)&hq_s[(m*16 + col)*ASTR + ks*32 + (rowq << 1)];
                #pragma unroll
                for (int j = 0; j < 4; ++j)
                    acc[j] = __builtin_amdgcn_mfma_f32_16x16x32_bf16(af, wa[j][ks], acc[j], 0, 0, 0);
            }
            // in-register activation (wave-uniform branch per j)
            #pragma unroll
            for (int j = 0; j < 4; ++j) {
                const int nt = wv + 8*j;
                const int kp = nt*16 + col;
                const float bias = BA_l[kp];
                if (nt < 12) {
                    // rr: P[b][kp] = sigmoid(val) * hu[kp]; hu = [hl|ht|hd] = HF{1,0,2}
                    const int sel = (nt >> 2);
                    const float* Hsel = HF + ((sel == 0) ? 1 : (sel == 1) ? 0 : 2)*64*68;
                    const int uoff = (nt & 3)*16 + col;
                    #pragma unroll
                    for (int reg = 0; reg < 4; ++reg) {
                        const int b = m*16 + rowq + reg;
                        const float val = acc[j][reg] + bias;
                        const float rr = 1.f / (1.f + __expf(-val));
                        P_s[b*ASTR + kp] = f2bf(rr * Hsel[b*68 + uoff]);
                    }
                } else if (nt < 28) {
                    // z: gate g = col&3 in quads [i,l,t,d]; softmax via shfl
                    const int g = col & 3;
                    const int u = (nt - 12)*4 + (col >> 2);
                    #pragma unroll
                    for (int reg = 0; reg < 4; ++reg) {
                        const int b = m*16 + rowq + reg;
                        const float val = acc[j][reg] + bias;
                        float mx = fmaxf(val, __shfl_xor(val, 1, 64));
                        mx = fmaxf(mx, __shfl_xor(mx, 2, 64));
                        const float ex = __expf(val - mx);
                        float s = ex + __shfl_xor(ex, 1, 64);
                        s += __shfl_xor(s, 2, 64);
                        const float gate = ex / s;
                        float hsel = 0.f;
                        if (g == 1)      hsel = HFv(1, b, u);
                        else if (g == 2) hsel = HFv(0, b, u);
                        else if (g == 3) hsel = HFv(2, b, u);
                        float tt = gate * hsel;
                        float s3 = tt + __shfl_xor(tt, 1, 64);
                        s3 += __shfl_xor(s3, 2, 64);
                        if (g == 0) { ZI_s[b*68 + u] = gate; ZH_s[b*68 + u] = s3; }
                    }
                }
                // nt >= 28: zero-pad tile, no output
            }
        }
        __syncthreads();   // P, ZH, ZI complete

        // ---- phase B GEMM (weights in regs) + epilogue ----
        {
            f32x4 acc2[2];
            acc2[0] = (f32x4){0,0,0,0}; acc2[1] = (f32x4){0,0,0,0};
            #pragma unroll
            for (int ks = 0; ks < 7; ++ks) {
                #pragma unroll
                for (int mi = 0; mi < 2; ++mi) {
                    s16x8 a2 = *(const s16x8*)&P_s[((mhB*2 + mi)*16 + col)*ASTR + ks*32 + (rowq << 1)];
                    acc2[mi] = __builtin_amdgcn_mfma_f32_16x16x32_bf16(a2, ub[ks], acc2[mi], 0, 0, 0);
                }
            }
            float* Hrow = Hout + ((size_t)(l*64 + r))*4096;
            const int u = nB*16 + col;
            const float wb = wij_b[u];
            #pragma unroll 1
            for (int mi = 0; mi < 2; ++mi) {
                #pragma unroll 1
                for (int reg = 0; reg < 4; ++reg) {
                    const int b = (mhB*2 + mi)*16 + rowq + reg;
                    const float hn = tanh_fast(acc2[mi][reg] + wb);
                    const float h = ZH_s[b*68 + u] + ZI_s[b*68 + u] * hn;
                    HFv(1, b, u) = h;                                   // hl for next step
                    if (l < 63) st_llc_f32(&Hrow[b*64 + u], h);         // write-through
                    else if (r == 63) out[b*64 + u] = h;
                }
            }
            // inline-asm stores are outside the compiler's barrier scoreboard:
            asm volatile("s_waitcnt vmcnt(0)" ::: "memory");
        }
        __syncthreads();

        // ---- publish row (l, r) ----
        if (tid == 0 && l < 63)
            set_flag(&flags[l*64 + r]);
    }
}

extern "C" void kernel_launch(void* const* d_in, const int* in_sizes, int n_in,
                              void* d_out, int out_size, void* d_ws, size_t ws_size,
                              hipStream_t stream)
{
    const float* inp   = (const float*)d_in[0];
    const float* wr_w  = (const float*)d_in[1];
    const float* wr_b  = (const float*)d_in[2];
    const float* wz_w  = (const float*)d_in[3];
    const float* wz_b  = (const float*)d_in[4];
    const float* wij_w = (const float*)d_in[5];
    const float* wij_b = (const float*)d_in[6];
    const float* U_w   = (const float*)d_in[7];
    float* out = (float*)d_out;

    unsigned short* WF = (unsigned short*)d_ws;
    unsigned short* UF = WF + N_WF;
    unsigned short* XT = UF + N_UF;
    float* fbase = (float*)(XT + N_XT);
    float* BAf   = fbase;                          // 512 floats
    float* Hout  = fbase + 512;                    // 64*64*4096 floats (64 MB)
    unsigned int* flags = (unsigned int*)(Hout + (size_t)64*64*4096);  // 4096 ints

    hipMemsetAsync(flags, 0, 64*64*sizeof(unsigned int), stream);
    prep_pack<<<66, 256, 0, stream>>>(wr_w, wr_b, wz_w, wz_b, wij_w, U_w, WF, UF, BAf);
    xpose<<<dim3(128, 32), 256, 0, stream>>>(inp, XT);

    hipFuncSetAttribute((const void*)gru_persist,
                        hipFuncAttributeMaxDynamicSharedMemorySize, SMEM_BYTES);
    gru_persist<<<64, 512, SMEM_BYTES, stream>>>(WF, UF, BAf, XT, wij_b, Hout, flags, out);
}

// Round 9
// 1543.834 us; speedup vs baseline: 5.2773x; 1.5671x over previous
//
#include <hip/hip_runtime.h>
#include <math.h>

// SpatialGRU persistent-wavefront kernel. B=64, C=16, L=64, R=64, U=64, D=208.
// 64 persistent blocks, block = grid row l; cells (l, r=0..63) sequential.
// Round 9: (1) shfl-free softmax via gate-per-register z-tile packing
// (wave wv>=4 owns gates i,l,t,d of u-block wv-4 as j=0..3);
// (2) phase-A ks 2..6 (hl/hd/x) pre-computed BEFORE the flag wait;
// (3) staging vectorized to float4/uint4 (kills 8-way LDS bank conflicts).
// Sync: atomic flag + sc0sc1 write-through payload (unchanged since r5).

typedef short s16x8 __attribute__((ext_vector_type(8)));
typedef float f32x4 __attribute__((ext_vector_type(4)));

#define ASTR 232                 // hq/P row stride (bf16 elems); 224 data + 8 pad
#define N_WF (32*7*512)          // shorts (32 N-tiles: 12 rr + 16 z + 4 zero pad)
#define N_UF (4*7*512)           // shorts
#define N_XT (4096*1024)         // shorts

// LDS layout (bytes)
#define OFF_HQ 0                 // [64][ASTR] bf16 = 29696
#define OFF_P  29696             // [64][ASTR] bf16 = 29696
#define OFF_HF 59392             // [3][64][68] f32 = 52224
#define OFF_ZH 111616            // [64][68] f32 = 17408
#define OFF_ZI 129024            // [64][68] f32 = 17408
#define OFF_BA 146432            // [512] f32 = 2048
#define SMEM_BYTES 148480

#define HFv(s,b,u)  HF[(((s)*64 + (b))*68) + (u)]

__device__ __forceinline__ unsigned short f2bf(float v) {
    unsigned int x = __float_as_uint(v);
    unsigned int r = (x + 0x7fffu + ((x >> 16) & 1u)) >> 16;
    return (unsigned short)r;
}
__device__ __forceinline__ unsigned int pack2(float a, float b) {
    return (unsigned int)f2bf(a) | ((unsigned int)f2bf(b) << 16);
}
__device__ __forceinline__ float tanh_fast(float x) {
    x = fminf(fmaxf(x, -15.f), 15.f);
    const float e = __expf(2.f * x);
    return (e - 1.f) / (e + 1.f);
}

// ---- LLC write-through payload stores / fresh-miss payload loads ----
__device__ __forceinline__ void st_llc_f32(float* p, float v) {
    asm volatile("global_store_dword %0, %1, off sc0 sc1" :: "v"(p), "v"(v) : "memory");
}
__device__ __forceinline__ void ld_llc_row32(const float* p, f32x4& a, f32x4& b) {
    asm volatile("global_load_dwordx4 %0, %2, off sc0 sc1\n\t"
                 "global_load_dwordx4 %1, %3, off sc0 sc1\n\t"
                 "s_waitcnt vmcnt(0)"
                 : "=&v"(a), "=&v"(b) : "v"(p), "v"(p + 4) : "memory");
}

// ---- coherence-point flag ops ----
__device__ __forceinline__ unsigned int poll_flag(unsigned int* p) {
    return __hip_atomic_fetch_add(p, 0u, __ATOMIC_RELAXED, __HIP_MEMORY_SCOPE_AGENT);
}
__device__ __forceinline__ void set_flag(unsigned int* p) {
    (void)__hip_atomic_fetch_add(p, 1u, __ATOMIC_RELAXED, __HIP_MEMORY_SCOPE_AGENT);
}

// ---- prep: pack weights into MFMA B-fragment lane order ----
// Tile map: nt 0..11 = rr rows kp=nt*16+c (wr_w row kp).
//           nt 12..27: g=(nt-12)>>2 (gate i,l,t,d), q=(nt-12)&3, u=q*16+c
//                      -> wz_w row g*64+u.   nt 28..31: zeros.
__global__ __launch_bounds__(256) void prep_pack(
    const float* __restrict__ wr_w, const float* __restrict__ wr_b,
    const float* __restrict__ wz_w, const float* __restrict__ wz_b,
    const float* __restrict__ wij_w, const float* __restrict__ U_w,
    unsigned short* __restrict__ WF, unsigned short* __restrict__ UF,
    float* __restrict__ BAf)
{
    int idx = blockIdx.x * 256 + threadIdx.x;
    if (idx < 32*7*64) {
        int frag = idx >> 6, lane = idx & 63;
        int nt = frag / 7, ks = frag % 7;
        int c  = lane & 15;
        int kb = ks*32 + ((lane >> 4) << 3);
        #pragma unroll
        for (int e = 0; e < 8; ++e) {
            int k = kb + e;
            float v = 0.f;
            if (k < 208) {
                if (nt < 12) v = wr_w[(nt*16 + c)*208 + k];
                else if (nt < 28) {
                    int g = (nt - 12) >> 2, q = (nt - 12) & 3;
                    v = wz_w[(g*64 + q*16 + c)*208 + k];
                }
            }
            WF[idx*8 + e] = f2bf(v);
        }
        return;
    }
    idx -= 32*7*64;
    if (idx < 4*7*64) {
        int frag = idx >> 6, lane = idx & 63;
        int t2 = frag / 7, ks = frag % 7;
        int u = t2*16 + (lane & 15);
        int kb = ks*32 + ((lane >> 4) << 3);
        #pragma unroll
        for (int e = 0; e < 8; ++e) {
            int k = kb + e;
            float v = 0.f;
            if (k < 192) v = U_w[u*192 + k];
            else if (k < 208) v = wij_w[u*16 + (k - 192)];
            UF[idx*8 + e] = f2bf(v);
        }
        return;
    }
    idx -= 4*7*64;
    if (idx < 512) {
        int nt = idx >> 4, c = idx & 15;
        float v = 0.f;
        if (nt < 12) v = wr_b[nt*16 + c];
        else if (nt < 28) {
            int g = (nt - 12) >> 2, q = (nt - 12) & 3;
            v = wz_b[g*64 + q*16 + c];
        }
        BAf[idx] = v;
    }
}

// ---- prep: transpose inputs (B,C,L,R) -> XT[(l,r)][(b,c)] bf16 ----
__global__ __launch_bounds__(256) void xpose(const float* __restrict__ inp,
                                             unsigned short* __restrict__ XT)
{
    __shared__ float tile[32][33];
    int bi = blockIdx.x;   // lr / 32
    int bj = blockIdx.y;   // bc / 32
    int tx = threadIdx.x & 31, ty = threadIdx.x >> 5;
    #pragma unroll
    for (int yy = 0; yy < 4; ++yy) {
        int bc = bj*32 + ty*4 + yy;
        tile[ty*4 + yy][tx] = inp[bc*4096 + bi*32 + tx];
    }
    __syncthreads();
    #pragma unroll
    for (int yy = 0; yy < 4; ++yy) {
        int lr = bi*32 + ty*4 + yy;
        XT[lr*1024 + bj*32 + tx] = f2bf(tile[tx][ty*4 + yy]);
    }
}

// ---- persistent wavefront ----
__global__ __launch_bounds__(512, 2) void gru_persist(
    const unsigned short* __restrict__ WF,
    const unsigned short* __restrict__ UF,
    const float* __restrict__ BAf,
    const unsigned short* __restrict__ XT,
    const float* __restrict__ wij_b,
    float* __restrict__ Hout,          // [l][r][b][u] fp32
    unsigned int* __restrict__ flags,  // [l][r]
    float* __restrict__ out)
{
    extern __shared__ char smem[];
    unsigned short* hq_s = (unsigned short*)(smem + OFF_HQ);
    unsigned short* P_s  = (unsigned short*)(smem + OFF_P);
    float* HF   = (float*)(smem + OFF_HF);
    float* ZH_s = (float*)(smem + OFF_ZH);
    float* ZI_s = (float*)(smem + OFF_ZI);
    float* BA_l = (float*)(smem + OFF_BA);

    const int tid = threadIdx.x;
    const int l = ((blockIdx.x & 7) << 3) | (blockIdx.x >> 3);   // XCD swizzle

    // init: HF zero; hq/P K-pad cols [208,232) zero; bias to LDS
    for (int i = tid; i < 3*64*68; i += 512) HF[i] = 0.f;
    for (int i = tid; i < 64*24; i += 512) {
        int b = i/24, cc = 208 + (i % 24);
        hq_s[b*ASTR + cc] = 0; P_s[b*ASTR + cc] = 0;
    }
    BA_l[tid] = BAf[tid];

    const int wv = tid >> 6, lane = tid & 63;
    const int col = lane & 15, rowq = (lane >> 4) << 2;
    const int sb = tid >> 3, su = (tid & 7) * 8;             // staging ownership
    const int nB = wv >> 1, mhB = wv & 1;                    // phase B tile

    // tile assignment: waves 0-3 -> 3 rr tiles + 1 pad; waves 4-7 -> 4 gates
    int ntj[4];
    #pragma unroll
    for (int j = 0; j < 4; ++j)
        ntj[j] = (wv < 4) ? ((j < 3) ? wv*3 + j : 28 + wv)
                          : (12 + (wv - 4) + 4*j);

    // ---- load weights into registers ONCE ----
    s16x8 wa[4][7];
    #pragma unroll
    for (int j = 0; j < 4; ++j)
        #pragma unroll
        for (int ks = 0; ks < 7; ++ks) {
            wa[j][ks] = *(const s16x8*)&WF[((ntj[j]*7 + ks)*64 + lane)*8];
            asm volatile("" : "+v"(wa[j][ks]));
        }
    s16x8 ub[7];
    #pragma unroll
    for (int ks = 0; ks < 7; ++ks)
        ub[ks] = *(const s16x8*)&UF[((nB*7 + ks)*64 + lane)*8];
    __syncthreads();

    #pragma unroll 1
    for (int r = 0; r < 64; ++r) {
        // ---- staging part 1 (no top dependency), vectorized 16B ----
        {
            f32x4 o0 = *(const f32x4*)&HFv(0, sb, su);
            f32x4 o1 = *(const f32x4*)&HFv(0, sb, su + 4);
            f32x4 l0 = *(const f32x4*)&HFv(1, sb, su);
            f32x4 l1 = *(const f32x4*)&HFv(1, sb, su + 4);
            *(f32x4*)&HFv(2, sb, su)     = o0;               // hd <- old ht
            *(f32x4*)&HFv(2, sb, su + 4) = o1;
            uint4 hlp, hdp;
            hlp.x = pack2(l0[0], l0[1]); hlp.y = pack2(l0[2], l0[3]);
            hlp.z = pack2(l1[0], l1[1]); hlp.w = pack2(l1[2], l1[3]);
            hdp.x = pack2(o0[0], o0[1]); hdp.y = pack2(o0[2], o0[3]);
            hdp.z = pack2(o1[0], o1[1]); hdp.w = pack2(o1[2], o1[3]);
            *(uint4*)&hq_s[sb*ASTR +  64 + su] = hlp;        // hl
            *(uint4*)&hq_s[sb*ASTR + 128 + su] = hdp;        // hd
            if (su < 16) {
                uint4 xv = *(const uint4*)&XT[((size_t)(l*64 + r))*1024 + sb*16 + su];
                *(uint4*)&hq_s[sb*ASTR + 192 + su] = xv;
                *(uint4*)&P_s [sb*ASTR + 192 + su] = xv;
            }
        }
        __syncthreads();

        // ---- phase A pre-wait: ks 2..6 (hl | hd | x contributions) ----
        f32x4 acc[4][4];
        #pragma unroll
        for (int m = 0; m < 4; ++m)
            #pragma unroll
            for (int j = 0; j < 4; ++j) acc[m][j] = (f32x4){0.f, 0.f, 0.f, 0.f};
        #pragma unroll
        for (int ks = 2; ks < 7; ++ks) {
            #pragma unroll
            for (int m = 0; m < 4; ++m) {
                s16x8 af = *(const s16x8*)&hq_s[(m*16 + col)*ASTR + ks*32 + (rowq << 1)];
                #pragma unroll
                for (int j = 0; j < 4; ++j)
                    acc[m][j] = __builtin_amdgcn_mfma_f32_16x16x32_bf16(af, wa[j][ks], acc[m][j], 0, 0, 0);
            }
        }

        // ---- wait for top row (l-1, r): coherent atomic poll ----
        if (l > 0 && tid == 0) {
            while (poll_flag(&flags[(l-1)*64 + r]) == 0u)
                __builtin_amdgcn_s_sleep(1);
        }
        __syncthreads();

        // ---- staging part 2: ht <- row (l-1, r), vectorized ----
        {
            f32x4 a = (f32x4){0,0,0,0}, b4 = (f32x4){0,0,0,0};
            if (l > 0) {
                const float* Hrow = Hout + ((size_t)((l-1)*64 + r))*4096 + sb*64 + su;
                ld_llc_row32(Hrow, a, b4);
            }
            *(f32x4*)&HFv(0, sb, su)     = a;
            *(f32x4*)&HFv(0, sb, su + 4) = b4;
            uint4 htp;
            htp.x = pack2(a[0], a[1]);  htp.y = pack2(a[2], a[3]);
            htp.z = pack2(b4[0], b4[1]); htp.w = pack2(b4[2], b4[3]);
            *(uint4*)&hq_s[sb*ASTR + su] = htp;              // ht
        }
        __syncthreads();

        // ---- phase A post-wait: ks 0..1 (ht contribution) + activation ----
        #pragma unroll
        for (int m = 0; m < 4; ++m) {
            #pragma unroll
            for (int ks = 0; ks < 2; ++ks) {
                s16x8 af = *(const s16x8*)&hq_s[(m*16 + col)*ASTR + ks*32 + (rowq << 1)];
                #pragma unroll
                for (int j = 0; j < 4; ++j)
                    acc[m][j] = __builtin_amdgcn_mfma_f32_16x16x32_bf16(af, wa[j][ks], acc[m][j], 0, 0, 0);
            }
            if (wv < 4) {
                // rr: P[b][kp] = sigmoid(val) * hu[kp]; hu = [hl|ht|hd] = HF{1,0,2}
                #pragma unroll
                for (int j = 0; j < 3; ++j) {
                    const int nt = wv*3 + j;
                    const int kp = nt*16 + col;
                    const float bias = BA_l[kp];
                    const int sel = nt >> 2;
                    const float* Hsel = HF + ((sel == 0) ? 1 : (sel == 1) ? 0 : 2)*64*68;
                    const int uoff = kp & 63;
                    #pragma unroll
                    for (int reg = 0; reg < 4; ++reg) {
                        const int b = m*16 + rowq + reg;
                        const float val = acc[m][j][reg] + bias;
                        const float rr = 1.f / (1.f + __expf(-val));
                        P_s[b*ASTR + kp] = f2bf(rr * Hsel[b*68 + uoff]);
                    }
                }
            } else {
                // z: lane holds all 4 gates of (b, uz) in acc[m][0..3][reg]
                const int uz = (wv - 4)*16 + col;
                const float bi = BA_l[(12 + (wv-4) +  0)*16 + col];
                const float bl = BA_l[(12 + (wv-4) +  4)*16 + col];
                const float bt = BA_l[(12 + (wv-4) +  8)*16 + col];
                const float bd = BA_l[(12 + (wv-4) + 12)*16 + col];
                #pragma unroll
                for (int reg = 0; reg < 4; ++reg) {
                    const int b = m*16 + rowq + reg;
                    const float vi = acc[m][0][reg] + bi;
                    const float vl = acc[m][1][reg] + bl;
                    const float vt = acc[m][2][reg] + bt;
                    const float vd = acc[m][3][reg] + bd;
                    const float mx = fmaxf(fmaxf(vi, vl), fmaxf(vt, vd));
                    const float ei = __expf(vi - mx);
                    const float el = __expf(vl - mx);
                    const float et = __expf(vt - mx);
                    const float ed = __expf(vd - mx);
                    const float inv = 1.f / (ei + el + et + ed);
                    const float hl = HFv(1, b, uz);
                    const float ht = HFv(0, b, uz);
                    const float hd = HFv(2, b, uz);
                    ZI_s[b*68 + uz] = ei * inv;
                    ZH_s[b*68 + uz] = (el*hl + et*ht + ed*hd) * inv;
                }
            }
        }
        __syncthreads();   // P, ZH, ZI complete

        // ---- phase B GEMM (weights in regs) + epilogue ----
        {
            f32x4 acc2[2];
            acc2[0] = (f32x4){0,0,0,0}; acc2[1] = (f32x4){0,0,0,0};
            #pragma unroll
            for (int ks = 0; ks < 7; ++ks) {
                #pragma unroll
                for (int mi = 0; mi < 2; ++mi) {
                    s16x8 a2 = *(const s16x8*)&P_s[((mhB*2 + mi)*16 + col)*ASTR + ks*32 + (rowq << 1)];
                    acc2[mi] = __builtin_amdgcn_mfma_f32_16x16x32_bf16(a2, ub[ks], acc2[mi], 0, 0, 0);
                }
            }
            float* Hrow = Hout + ((size_t)(l*64 + r))*4096;
            const int u = nB*16 + col;
            const float wb = wij_b[u];
            #pragma unroll 1
            for (int mi = 0; mi < 2; ++mi) {
                #pragma unroll 1
                for (int reg = 0; reg < 4; ++reg) {
                    const int b = (mhB*2 + mi)*16 + rowq + reg;
                    const float hn = tanh_fast(acc2[mi][reg] + wb);
                    const float h = ZH_s[b*68 + u] + ZI_s[b*68 + u] * hn;
                    HFv(1, b, u) = h;                                   // hl for next step
                    if (l < 63) st_llc_f32(&Hrow[b*64 + u], h);         // write-through
                    else if (r == 63) out[b*64 + u] = h;
                }
            }
            // inline-asm stores are outside the compiler's barrier scoreboard:
            asm volatile("s_waitcnt vmcnt(0)" ::: "memory");
        }
        __syncthreads();

        // ---- publish row (l, r) ----
        if (tid == 0 && l < 63)
            set_flag(&flags[l*64 + r]);
    }
}

extern "C" void kernel_launch(void* const* d_in, const int* in_sizes, int n_in,
                              void* d_out, int out_size, void* d_ws, size_t ws_size,
                              hipStream_t stream)
{
    const float* inp   = (const float*)d_in[0];
    const float* wr_w  = (const float*)d_in[1];
    const float* wr_b  = (const float*)d_in[2];
    const float* wz_w  = (const float*)d_in[3];
    const float* wz_b  = (const float*)d_in[4];
    const float* wij_w = (const float*)d_in[5];
    const float* wij_b = (const float*)d_in[6];
    const float* U_w   = (const float*)d_in[7];
    float* out = (float*)d_out;

    unsigned short* WF = (unsigned short*)d_ws;
    unsigned short* UF = WF + N_WF;
    unsigned short* XT = UF + N_UF;
    float* fbase = (float*)(XT + N_XT);
    float* BAf   = fbase;                          // 512 floats
    float* Hout  = fbase + 512;                    // 64*64*4096 floats (64 MB)
    unsigned int* flags = (unsigned int*)(Hout + (size_t)64*64*4096);  // 4096 ints

    hipMemsetAsync(flags, 0, 64*64*sizeof(unsigned int), stream);
    prep_pack<<<66, 256, 0, stream>>>(wr_w, wr_b, wz_w, wz_b, wij_w, U_w, WF, UF, BAf);
    xpose<<<dim3(128, 32), 256, 0, stream>>>(inp, XT);

    hipFuncSetAttribute((const void*)gru_persist,
                        hipFuncAttributeMaxDynamicSharedMemorySize, SMEM_BYTES);
    gru_persist<<<64, 512, SMEM_BYTES, stream>>>(WF, UF, BAf, XT, wij_b, Hout, flags, out);
}

// Round 10
// 418.137 us; speedup vs baseline: 19.4847x; 3.6922x over previous
//
#include <hip/hip_runtime.h>
#include <math.h>

// SpatialGRU persistent-wavefront kernel. B=64, C=16, L=64, R=64, U=64, D=208.
// Round 10: 256 persistent blocks = (64 rows l) x (4 batch quarters of 16).
// Quarters are independent pipelines (batch doesn't couple). One block/CU.
// Sync: NO flag — Hout poisoned 0xFFFFFFFF (-NaN) per launch; consumers spin
// on their own ht chunk via sc0sc1 loads until all 8 dwords are non-poison.
// Phase A: [16 b x 448 kp] = hq[16x224] @ W^T   (bf16 MFMA 16x16x32)
// Phase B: [16 b x 64 u]   = P [16x224] @ U2^T  (P = rr.*hu | x)

typedef short s16x8 __attribute__((ext_vector_type(8)));
typedef float f32x4 __attribute__((ext_vector_type(4)));

#define ASTR 232                 // hq/P row stride (bf16 elems); 224 data + 8 pad
#define N_WF (32*7*512)          // shorts (32 N-tiles: 12 rr + 16 z + 4 zero pad)
#define N_UF (4*7*512)           // shorts
#define N_XT (4096*1024)         // shorts
#define POISON 0xFFFFFFFFu       // -NaN; h is always finite

// LDS layout (bytes), 16 batch rows per block
#define OFF_HQ 0                 // [16][ASTR] bf16 = 7424
#define OFF_P  7424              // [16][ASTR] bf16 = 7424
#define OFF_HF 14848             // [3][16][68] f32 = 13056
#define OFF_ZH 27904             // [16][68] f32 = 4352
#define OFF_ZI 32256             // [16][68] f32 = 4352
#define OFF_BA 36608             // [512] f32 = 2048
#define SMEM_BYTES 38656

#define HFv(s,b,u)  HF[(((s)*16 + (b))*68) + (u)]

__device__ __forceinline__ unsigned short f2bf(float v) {
    unsigned int x = __float_as_uint(v);
    unsigned int r = (x + 0x7fffu + ((x >> 16) & 1u)) >> 16;
    return (unsigned short)r;
}
__device__ __forceinline__ unsigned int pack2(float a, float b) {
    return (unsigned int)f2bf(a) | ((unsigned int)f2bf(b) << 16);
}
__device__ __forceinline__ float tanh_fast(float x) {
    x = fminf(fmaxf(x, -15.f), 15.f);
    const float e = __expf(2.f * x);
    return (e - 1.f) / (e + 1.f);
}

// ---- LLC write-through payload stores ----
__device__ __forceinline__ void st_llc_f32(float* p, float v) {
    asm volatile("global_store_dword %0, %1, off sc0 sc1" :: "v"(p), "v"(v) : "memory");
}

// ---- prep: pack weights into MFMA B-fragment lane order ----
// nt 0..11 = rr rows kp=nt*16+c. nt 12..27: g=(nt-12)>>2 (gate i,l,t,d),
// q=(nt-12)&3, u=q*16+c -> wz_w row g*64+u. nt 28..31: zeros.
__global__ __launch_bounds__(256) void prep_pack(
    const float* __restrict__ wr_w, const float* __restrict__ wr_b,
    const float* __restrict__ wz_w, const float* __restrict__ wz_b,
    const float* __restrict__ wij_w, const float* __restrict__ U_w,
    unsigned short* __restrict__ WF, unsigned short* __restrict__ UF,
    float* __restrict__ BAf)
{
    int idx = blockIdx.x * 256 + threadIdx.x;
    if (idx < 32*7*64) {
        int frag = idx >> 6, lane = idx & 63;
        int nt = frag / 7, ks = frag % 7;
        int c  = lane & 15;
        int kb = ks*32 + ((lane >> 4) << 3);
        #pragma unroll
        for (int e = 0; e < 8; ++e) {
            int k = kb + e;
            float v = 0.f;
            if (k < 208) {
                if (nt < 12) v = wr_w[(nt*16 + c)*208 + k];
                else if (nt < 28) {
                    int g = (nt - 12) >> 2, q = (nt - 12) & 3;
                    v = wz_w[(g*64 + q*16 + c)*208 + k];
                }
            }
            WF[idx*8 + e] = f2bf(v);
        }
        return;
    }
    idx -= 32*7*64;
    if (idx < 4*7*64) {
        int frag = idx >> 6, lane = idx & 63;
        int t2 = frag / 7, ks = frag % 7;
        int u = t2*16 + (lane & 15);
        int kb = ks*32 + ((lane >> 4) << 3);
        #pragma unroll
        for (int e = 0; e < 8; ++e) {
            int k = kb + e;
            float v = 0.f;
            if (k < 192) v = U_w[u*192 + k];
            else if (k < 208) v = wij_w[u*16 + (k - 192)];
            UF[idx*8 + e] = f2bf(v);
        }
        return;
    }
    idx -= 4*7*64;
    if (idx < 512) {
        int nt = idx >> 4, c = idx & 15;
        float v = 0.f;
        if (nt < 12) v = wr_b[nt*16 + c];
        else if (nt < 28) {
            int g = (nt - 12) >> 2, q = (nt - 12) & 3;
            v = wz_b[g*64 + q*16 + c];
        }
        BAf[idx] = v;
    }
}

// ---- prep: transpose inputs (B,C,L,R) -> XT[(l,r)][(b,c)] bf16 ----
__global__ __launch_bounds__(256) void xpose(const float* __restrict__ inp,
                                             unsigned short* __restrict__ XT)
{
    __shared__ float tile[32][33];
    int bi = blockIdx.x;   // lr / 32
    int bj = blockIdx.y;   // bc / 32
    int tx = threadIdx.x & 31, ty = threadIdx.x >> 5;
    #pragma unroll
    for (int yy = 0; yy < 4; ++yy) {
        int bc = bj*32 + ty*4 + yy;
        tile[ty*4 + yy][tx] = inp[bc*4096 + bi*32 + tx];
    }
    __syncthreads();
    #pragma unroll
    for (int yy = 0; yy < 4; ++yy) {
        int lr = bi*32 + ty*4 + yy;
        XT[lr*1024 + bj*32 + tx] = f2bf(tile[tx][ty*4 + yy]);
    }
}

// ---- persistent wavefront ----
__global__ __launch_bounds__(512, 2) void gru_persist(
    const unsigned short* __restrict__ WF,
    const unsigned short* __restrict__ UF,
    const float* __restrict__ BAf,
    const unsigned short* __restrict__ XT,
    const float* __restrict__ wij_b,
    float* __restrict__ Hout,          // [l][r][b(64)][u(64)] fp32, poisoned
    float* __restrict__ out)
{
    extern __shared__ char smem[];
    unsigned short* hq_s = (unsigned short*)(smem + OFF_HQ);
    unsigned short* P_s  = (unsigned short*)(smem + OFF_P);
    float* HF   = (float*)(smem + OFF_HF);
    float* ZH_s = (float*)(smem + OFF_ZH);
    float* ZI_s = (float*)(smem + OFF_ZI);
    float* BA_l = (float*)(smem + OFF_BA);

    const int tid = threadIdx.x;
    const int q  = blockIdx.x >> 6;                               // batch quarter
    const int i  = blockIdx.x & 63;
    const int l  = ((i & 7) << 3) | (i >> 3);                     // XCD swizzle
    const int b0 = q * 16;

    // init: HF zero; hq/P K-pad cols [208,232) zero; bias to LDS
    for (int k = tid; k < 3*16*68; k += 512) HF[k] = 0.f;
    for (int k = tid; k < 16*24; k += 512) {
        int b = k/24, cc = 208 + (k % 24);
        hq_s[b*ASTR + cc] = 0; P_s[b*ASTR + cc] = 0;
    }
    BA_l[tid] = BAf[tid];

    const int wv = tid >> 6, lane = tid & 63;
    const int col = lane & 15, rowq = (lane >> 4) << 2;
    // staging: 16 active lanes per wave (one per (sb,su) pair)
    const bool act = (tid & 3) == 0;
    const int sb = tid >> 5;                 // 0..15 local batch row
    const int su = ((tid >> 2) & 7) * 8;     // 0..56, 8 floats each

    // tile assignment: waves 0-3 -> 3 rr tiles + pad; waves 4-7 -> 4 gates
    int ntj[4];
    #pragma unroll
    for (int j = 0; j < 4; ++j)
        ntj[j] = (wv < 4) ? ((j < 3) ? wv*3 + j : 28 + wv)
                          : (12 + (wv - 4) + 4*j);

    // ---- load weights into registers ONCE ----
    s16x8 wa[4][7];
    #pragma unroll
    for (int j = 0; j < 4; ++j)
        #pragma unroll
        for (int ks = 0; ks < 7; ++ks) {
            wa[j][ks] = *(const s16x8*)&WF[((ntj[j]*7 + ks)*64 + lane)*8];
            asm volatile("" : "+v"(wa[j][ks]));
        }
    s16x8 ub[7];
    if (wv < 4) {
        #pragma unroll
        for (int ks = 0; ks < 7; ++ks)
            ub[ks] = *(const s16x8*)&UF[((wv*7 + ks)*64 + lane)*8];
    }
    __syncthreads();

    #pragma unroll 1
    for (int r = 0; r < 64; ++r) {
        // ---- staging 1 (no top dependency): hd <- old ht; hl; x ----
        if (act) {
            f32x4 o0 = *(const f32x4*)&HFv(0, sb, su);
            f32x4 o1 = *(const f32x4*)&HFv(0, sb, su + 4);
            f32x4 l0 = *(const f32x4*)&HFv(1, sb, su);
            f32x4 l1 = *(const f32x4*)&HFv(1, sb, su + 4);
            *(f32x4*)&HFv(2, sb, su)     = o0;               // hd <- old ht
            *(f32x4*)&HFv(2, sb, su + 4) = o1;
            uint4 hlp, hdp;
            hlp.x = pack2(l0[0], l0[1]); hlp.y = pack2(l0[2], l0[3]);
            hlp.z = pack2(l1[0], l1[1]); hlp.w = pack2(l1[2], l1[3]);
            hdp.x = pack2(o0[0], o0[1]); hdp.y = pack2(o0[2], o0[3]);
            hdp.z = pack2(o1[0], o1[1]); hdp.w = pack2(o1[2], o1[3]);
            *(uint4*)&hq_s[sb*ASTR +  64 + su] = hlp;        // hl
            *(uint4*)&hq_s[sb*ASTR + 128 + su] = hdp;        // hd
            if (su < 16) {
                uint4 xv = *(const uint4*)&XT[((size_t)(l*64 + r))*1024 + (b0 + sb)*16 + su];
                *(uint4*)&hq_s[sb*ASTR + 192 + su] = xv;
                *(uint4*)&P_s [sb*ASTR + 192 + su] = xv;
            }
        }
        __syncthreads();

        // ---- phase A pre-wait: ks 2..6 (hl | hd | x contributions) ----
        f32x4 acc[4];
        #pragma unroll
        for (int j = 0; j < 4; ++j) acc[j] = (f32x4){0.f, 0.f, 0.f, 0.f};
        #pragma unroll
        for (int ks = 2; ks < 7; ++ks) {
            s16x8 af = *(const s16x8*)&hq_s[col*ASTR + ks*32 + (rowq << 1)];
            #pragma unroll
            for (int j = 0; j < 4; ++j)
                acc[j] = __builtin_amdgcn_mfma_f32_16x16x32_bf16(af, wa[j][ks], acc[j], 0, 0, 0);
        }

        // ---- staging 2 = sync: spin on ht chunk until non-poison ----
        if (act) {
            f32x4 a = (f32x4){0,0,0,0}, b4 = (f32x4){0,0,0,0};
            if (l > 0) {
                const float* p = Hout + ((size_t)((l-1)*64 + r))*4096 + (b0 + sb)*64 + su;
                uint4 A, B;
                do {
                    asm volatile("global_load_dwordx4 %0, %2, off sc0 sc1\n\t"
                                 "global_load_dwordx4 %1, %3, off sc0 sc1\n\t"
                                 "s_waitcnt vmcnt(0)"
                                 : "=&v"(A), "=&v"(B) : "v"(p), "v"(p + 4) : "memory");
                } while (A.x == POISON || A.y == POISON || A.z == POISON || A.w == POISON ||
                         B.x == POISON || B.y == POISON || B.z == POISON || B.w == POISON);
                a[0] = __uint_as_float(A.x); a[1] = __uint_as_float(A.y);
                a[2] = __uint_as_float(A.z); a[3] = __uint_as_float(A.w);
                b4[0] = __uint_as_float(B.x); b4[1] = __uint_as_float(B.y);
                b4[2] = __uint_as_float(B.z); b4[3] = __uint_as_float(B.w);
            }
            *(f32x4*)&HFv(0, sb, su)     = a;
            *(f32x4*)&HFv(0, sb, su + 4) = b4;
            uint4 htp;
            htp.x = pack2(a[0], a[1]);   htp.y = pack2(a[2], a[3]);
            htp.z = pack2(b4[0], b4[1]); htp.w = pack2(b4[2], b4[3]);
            *(uint4*)&hq_s[sb*ASTR + su] = htp;              // ht
        }
        __syncthreads();

        // ---- phase A post-wait: ks 0..1 (ht contribution) + activation ----
        #pragma unroll
        for (int ks = 0; ks < 2; ++ks) {
            s16x8 af = *(const s16x8*)&hq_s[col*ASTR + ks*32 + (rowq << 1)];
            #pragma unroll
            for (int j = 0; j < 4; ++j)
                acc[j] = __builtin_amdgcn_mfma_f32_16x16x32_bf16(af, wa[j][ks], acc[j], 0, 0, 0);
        }
        if (wv < 4) {
            // rr: P[b][kp] = sigmoid(val) * hu[kp]; hu = [hl|ht|hd] = HF{1,0,2}
            #pragma unroll
            for (int j = 0; j < 3; ++j) {
                const int nt = wv*3 + j;
                const int kp = nt*16 + col;
                const float bias = BA_l[kp];
                const int sel = nt >> 2;
                const float* Hsel = HF + ((sel == 0) ? 1 : (sel == 1) ? 0 : 2)*16*68;
                const int uoff = kp & 63;
                #pragma unroll
                for (int reg = 0; reg < 4; ++reg) {
                    const int b = rowq + reg;
                    const float val = acc[j][reg] + bias;
                    const float rr = 1.f / (1.f + __expf(-val));
                    P_s[b*ASTR + kp] = f2bf(rr * Hsel[b*68 + uoff]);
                }
            }
        } else {
            // z: lane holds all 4 gates of (b, uz) in acc[0..3][reg]
            const int uz = (wv - 4)*16 + col;
            const float bi = BA_l[(12 + (wv-4) +  0)*16 + col];
            const float bl = BA_l[(12 + (wv-4) +  4)*16 + col];
            const float bt = BA_l[(12 + (wv-4) +  8)*16 + col];
            const float bd = BA_l[(12 + (wv-4) + 12)*16 + col];
            #pragma unroll
            for (int reg = 0; reg < 4; ++reg) {
                const int b = rowq + reg;
                const float vi = acc[0][reg] + bi;
                const float vl = acc[1][reg] + bl;
                const float vt = acc[2][reg] + bt;
                const float vd = acc[3][reg] + bd;
                const float mx = fmaxf(fmaxf(vi, vl), fmaxf(vt, vd));
                const float ei = __expf(vi - mx);
                const float el = __expf(vl - mx);
                const float et = __expf(vt - mx);
                const float ed = __expf(vd - mx);
                const float inv = 1.f / (ei + el + et + ed);
                const float hl = HFv(1, b, uz);
                const float ht = HFv(0, b, uz);
                const float hd = HFv(2, b, uz);
                ZI_s[b*68 + uz] = ei * inv;
                ZH_s[b*68 + uz] = (el*hl + et*ht + ed*hd) * inv;
            }
        }
        __syncthreads();   // P, ZH, ZI complete

        // ---- phase B GEMM (waves 0-3, one u-tile each) + epilogue ----
        if (wv < 4) {
            f32x4 acc2 = (f32x4){0,0,0,0};
            #pragma unroll
            for (int ks = 0; ks < 7; ++ks) {
                s16x8 a2 = *(const s16x8*)&P_s[col*ASTR + ks*32 + (rowq << 1)];
                acc2 = __builtin_amdgcn_mfma_f32_16x16x32_bf16(a2, ub[ks], acc2, 0, 0, 0);
            }
            float* Hrow = Hout + ((size_t)(l*64 + r))*4096;
            const int u = wv*16 + col;
            const float wb = wij_b[u];
            #pragma unroll 1
            for (int reg = 0; reg < 4; ++reg) {
                const int b = rowq + reg;
                const float hn = tanh_fast(acc2[reg] + wb);
                const float h = ZH_s[b*68 + u] + ZI_s[b*68 + u] * hn;
                HFv(1, b, u) = h;                                   // hl for next step
                if (l < 63) st_llc_f32(&Hrow[(b0 + b)*64 + u], h);  // write-through
                else if (r == 63) out[(b0 + b)*64 + u] = h;
            }
        }
        __syncthreads();
    }
}

extern "C" void kernel_launch(void* const* d_in, const int* in_sizes, int n_in,
                              void* d_out, int out_size, void* d_ws, size_t ws_size,
                              hipStream_t stream)
{
    const float* inp   = (const float*)d_in[0];
    const float* wr_w  = (const float*)d_in[1];
    const float* wr_b  = (const float*)d_in[2];
    const float* wz_w  = (const float*)d_in[3];
    const float* wz_b  = (const float*)d_in[4];
    const float* wij_w = (const float*)d_in[5];
    const float* wij_b = (const float*)d_in[6];
    const float* U_w   = (const float*)d_in[7];
    float* out = (float*)d_out;

    unsigned short* WF = (unsigned short*)d_ws;
    unsigned short* UF = WF + N_WF;
    unsigned short* XT = UF + N_UF;
    float* fbase = (float*)(XT + N_XT);
    float* BAf   = fbase;                          // 512 floats
    float* Hout  = fbase + 512;                    // 64*64*4096 floats (64 MB)

    // poison the H ring: 0xFF bytes = -NaN dwords (h is always finite)
    hipMemsetAsync(Hout, 0xFF, (size_t)64*64*4096*sizeof(float), stream);
    prep_pack<<<66, 256, 0, stream>>>(wr_w, wr_b, wz_w, wz_b, wij_w, U_w, WF, UF, BAf);
    xpose<<<dim3(128, 32), 256, 0, stream>>>(inp, XT);

    gru_persist<<<256, 512, SMEM_BYTES, stream>>>(WF, UF, BAf, XT, wij_b, Hout, out);
}